// Round 14
// baseline (205.512 us; speedup 1.0000x reference)
//
#include <hip/hip_runtime.h>
#include <hip/hip_bf16.h>

#define N2   4096    // 64*64 attn pixels
#define HWP  16384   // 128*128
#define EPSI 1e-5f

typedef unsigned short ushort_t;
typedef __attribute__((ext_vector_type(8))) short short8;
typedef __attribute__((ext_vector_type(4))) float f32x4;

// ---- workspace layout (f32-word offsets), peak 18,089,024 words = 72.4 MB ----
static const size_t BUF0_OFF  = 0;          // bf16 [2][16384][256]
static const size_t BUF1_OFF  = 4194304;    // bf16 [2][16384][256]  (later y3)
static const size_t QT_OFF    = 8388608;    // bf16 [2][4096][256]  q pixel-major (gamma/8 folded)
static const size_t KC_OFF    = 9437184;    // bf16 [2][256][4096]  k channel-major; later M[2][256][256]
static const size_t VC_OFF    = 10485760;   // bf16 [2][256][4096]
static const size_t S_OFF     = 11534336;   // f32 [8][64][64]   --- zero region start
static const size_t SUM_OFF   = 11567104;   // f32 [512]
static const size_t SUM2_OFF  = 11567616;   // f32 [512]
static const size_t ZP_OFF    = 11568128;   // f32 [64] zero page --- zero region end (33,856)
static const size_t XCAT_OFF  = 11568192;   // bf16 [2][16384][256] conv1x1 out pixel-major
static const size_t PREVT_OFF = 15762496;   // bf16 [2][4096][256]  prev pixel-major (unpadded)
static const size_t WQ_OFF    = 16811072;   // bf16 [4][256][256]
static const size_t WK_OFF    = 16942144;
static const size_t WV_OFF    = 17073216;
static const size_t WF_OFF    = 17204288;   // bf16 [256][512]
static const size_t WA3X_OFF  = 17269824;   // bf16 [9][256][256]  3x3 weights, xcat channels
static const size_t WPP_OFF   = 17564736;   // bf16 [16][256][256] row+col-collapsed prev weights
static const size_t Y3_OFF    = BUF1_OFF;
static const size_t M_OFF     = KC_OFF;     // bf16 [2][256][256] = W_att x S (aliases dead k)

__device__ __forceinline__ ushort_t f2bf(float x) {
    union { float f; unsigned u; } v; v.f = x;
    unsigned r = v.u + 0x7FFFu + ((v.u >> 16) & 1u);
    return (ushort_t)(r >> 16);
}
__device__ __forceinline__ float bf2f(ushort_t h) {
    union { unsigned u; float f; } v; v.u = ((unsigned)h) << 16; return v.f;
}
__device__ __forceinline__ void gload_lds16(const void* g, void* l) {
    __builtin_amdgcn_global_load_lds(
        (const __attribute__((address_space(1))) void*)g,
        (__attribute__((address_space(3))) void*)l, 16, 0, 0);
}

// ---------------- prep: weight packs + prevT + zero-init ----------------
__global__ __launch_bounds__(256) void prep_k(const float* __restrict__ qw,
                                              const float* __restrict__ kw,
                                              const float* __restrict__ vw,
                                              const float* __restrict__ fw,
                                              const float* __restrict__ cw,
                                              const float* __restrict__ prev,
                                              float* __restrict__ wsf) {
    __shared__ ushort_t T[64][64];
    int sec = blockIdx.y, bx = blockIdx.x, t = threadIdx.x;
    if (sec < 3) {               // pack q/k/v weights: [oc][c][2][2] -> wA[tap][oc][c]
        if (bx >= 256) return;
        int idx = bx * 256 + t;
        const float* src = sec == 0 ? qw : (sec == 1 ? kw : vw);
        ushort_t* dst = (ushort_t*)(wsf + (sec == 0 ? WQ_OFF : (sec == 1 ? WK_OFF : WV_OFF)));
        float4 v = *(const float4*)&src[(size_t)idx * 4];
        dst[0 * 65536 + idx] = f2bf(v.x);
        dst[1 * 65536 + idx] = f2bf(v.y);
        dst[2 * 65536 + idx] = f2bf(v.z);
        dst[3 * 65536 + idx] = f2bf(v.w);
    } else if (sec == 3) {       // pack fw
        int idx = bx * 256 + t;
        ((ushort_t*)(wsf + WF_OFF))[idx] = f2bf(fw[idx]);
    } else if (sec == 4) {       // pack 3x3 weights: xcat taps + row+col-collapsed prev taps
        int idx = bx * 256 + t;  // oc*512 + c
        int oc = idx >> 9, c = idx & 511;
        const float* src = cw + (size_t)idx * 9;
        float w[9];
#pragma unroll
        for (int tp = 0; tp < 9; ++tp) w[tp] = src[tp];
        if (c < 256) {
            ushort_t* wA3x = (ushort_t*)(wsf + WA3X_OFF);
#pragma unroll
            for (int tp = 0; tp < 9; ++tp)
                wA3x[((size_t)tp * 256 + oc) * 256 + c] = f2bf(w[tp]);
        } else {
            int cc = c - 256;
            ushort_t* wPP = (ushort_t*)(wsf + WPP_OFF);
#pragma unroll
            for (int py = 0; py < 2; ++py) {
                float rs[2][3];
#pragma unroll
                for (int fx = 0; fx < 3; ++fx) {
                    if (py == 0) { rs[0][fx] = w[fx];           rs[1][fx] = w[3 + fx] + w[6 + fx]; }
                    else         { rs[0][fx] = w[fx] + w[3 + fx]; rs[1][fx] = w[6 + fx]; }
                }
#pragma unroll
                for (int pxp = 0; pxp < 2; ++pxp)
#pragma unroll
                    for (int j2 = 0; j2 < 2; ++j2) {
                        float v0 = pxp == 0 ? rs[j2][0] : rs[j2][0] + rs[j2][1];
                        float v1 = pxp == 0 ? rs[j2][1] + rs[j2][2] : rs[j2][2];
                        wPP[(((size_t)((py * 2 + pxp) * 4 + j2 * 2 + 0)) * 256 + oc) * 256 + cc] = f2bf(v0);
                        wPP[(((size_t)((py * 2 + pxp) * 4 + j2 * 2 + 1)) * 256 + oc) * 256 + cc] = f2bf(v1);
                    }
            }
        }
    } else if (sec == 5) {       // prevT: [b][256][64][64] -> [b][4096][256] (unpadded)
        int y2 = bx & 63, ct = (bx >> 6) & 3, b = bx >> 8;
        ushort_t* pT = (ushort_t*)(wsf + PREVT_OFF);
#pragma unroll
        for (int i = 0; i < 4; ++i) {
            int s = t + i * 256;
            int cc = s >> 4, xq = s & 15;
            float4 v = *(const float4*)&prev[(((size_t)b * 256 + ct * 64 + cc) * 64 + y2) * 64 + xq * 4];
            ushort4 h; h.x = f2bf(v.x); h.y = f2bf(v.y); h.z = f2bf(v.z); h.w = f2bf(v.w);
            *(ushort4*)&T[cc][xq * 4] = h;
        }
        __syncthreads();
#pragma unroll
        for (int i = 0; i < 2; ++i) {
            int w = t * 2 + i;
            int px = w >> 3, cbk = w & 7;
            short8 o;
#pragma unroll
            for (int j = 0; j < 8; ++j) o[j] = (short)T[cbk * 8 + j][px];
            *(short8*)&pT[((size_t)b * N2 + (size_t)y2 * 64 + px) * 256 + ct * 64 + cbk * 8] = o;
        }
    } else {                     // zero S/SUM/SUM2/ZP
        int idx = bx * 256 + t;
        if (idx < 33856) wsf[S_OFF + idx] = 0.f;
    }
}

// ---------------- input -> pixel-major bf16 ----------------
__device__ __forceinline__ void xpm_body(const float* __restrict__ in, ushort_t* __restrict__ xpm,
                                         int y, int ct, int b, int t) {
    __shared__ ushort_t T[64][128];
#pragma unroll
    for (int i = 0; i < 8; ++i) {
        int s = t + i * 256;
        int cc = s >> 5, xq = s & 31;
        float4 v = *(const float4*)&in[(((size_t)b * 256 + ct * 64 + cc) * 128 + y) * 128 + xq * 4];
        ushort4 h; h.x = f2bf(v.x); h.y = f2bf(v.y); h.z = f2bf(v.z); h.w = f2bf(v.w);
        *(ushort4*)&T[cc][xq * 4] = h;
    }
    __syncthreads();
#pragma unroll
    for (int i = 0; i < 4; ++i) {
        int w = t * 4 + i;
        int px = w >> 3, cbk = w & 7;
        short8 o;
#pragma unroll
        for (int j = 0; j < 8; ++j) o[j] = (short)T[cbk * 8 + j][px];
        *(short8*)&xpm[(((size_t)b * HWP) + (size_t)y * 128 + px) * 256 + ct * 64 + cbk * 8] = o;
    }
}

__global__ __launch_bounds__(256) void xpm2_k(const float* __restrict__ app,
                                              const float* __restrict__ app_pose,
                                              float* __restrict__ wsf) {
    int z = blockIdx.z, which = z >> 1, b = z & 1;
    const float* in = which == 0 ? app : app_pose;
    ushort_t* dst = (ushort_t*)(wsf + (which == 0 ? BUF0_OFF : BUF1_OFF));
    xpm_body(in, dst, blockIdx.x, blockIdx.y, b, threadIdx.x);
}

__global__ __launch_bounds__(256) void xpmP_k(const float* __restrict__ pose,
                                              float* __restrict__ wsf) {
    xpm_body(pose, (ushort_t*)(wsf + BUF0_OFF), blockIdx.x, blockIdx.y, blockIdx.z, threadIdx.x);
}

// ---------------- qkv stride-2 2x2 conv GEMM body ----------------
template<int MODE>
__device__ __forceinline__ void qkv_body(int nb, int oct, int b,
                                         const float* __restrict__ bias,
                                         const float* __restrict__ gamma,
                                         const ushort_t* __restrict__ wA,
                                         const ushort_t* __restrict__ xpm,
                                         ushort_t* __restrict__ outp) {
    int n0 = nb * 32, oc0 = oct * 128;
    __shared__ alignas(16) ushort_t As[2][128 * 64];
    __shared__ alignas(16) ushort_t Bs[2][32 * 64];
    int t = threadIdx.x, lane = t & 63, wv = t >> 6;
    int wm = wv >> 1, wn = wv & 1, l15 = lane & 15, lq = lane >> 4;
    f32x4 acc[4] = {};

    auto stage = [&](int chunk, int bufi) {
        int tap = chunk >> 2, c0 = (chunk & 3) << 6;
        int fy = tap >> 1, fx = tap & 1;
#pragma unroll
        for (int r = 0; r < 4; ++r) {
            int slot = t + r * 256;
            int row = slot >> 3, cbk = slot & 7;
            const ushort_t* src = wA + ((size_t)tap * 65536 + (size_t)(oc0 + row) * 256
                                        + c0 + ((cbk ^ (row & 7)) << 3));
            gload_lds16(src, (ushort_t*)As[bufi] + (((size_t)wv * 64 + r * 256) << 3));
        }
        {
            int n = t >> 3, cbk = t & 7;
            int ng = n0 + n;
            int iy = ((ng >> 6) << 1) + fy, ix = ((ng & 63) << 1) + fx;
            const ushort_t* src = xpm + (((size_t)b * HWP + (size_t)iy * 128 + ix) * 256
                                         + c0 + ((cbk ^ (n & 7)) << 3));
            gload_lds16(src, (ushort_t*)Bs[bufi] + ((size_t)wv * 64 << 3));
        }
    };

    stage(0, 0);
    __syncthreads();
    int buf = 0;
    for (int chunk = 0; chunk < 16; ++chunk) {
        short8 af[4][2], bf[2];
#pragma unroll
        for (int m = 0; m < 4; ++m) {
            int row = wm * 64 + m * 16 + l15;
#pragma unroll
            for (int ks = 0; ks < 2; ++ks)
                af[m][ks] = *(const short8*)&As[buf][row * 64 + (((ks * 4 + lq) ^ (row & 7)) << 3)];
        }
        {
            int col = wn * 16 + l15;
#pragma unroll
            for (int ks = 0; ks < 2; ++ks)
                bf[ks] = *(const short8*)&Bs[buf][col * 64 + (((ks * 4 + lq) ^ (col & 7)) << 3)];
        }
        if (chunk < 15) stage(chunk + 1, buf ^ 1);
#pragma unroll
        for (int ks = 0; ks < 2; ++ks)
#pragma unroll
            for (int m = 0; m < 4; ++m)
                acc[m] = __builtin_amdgcn_mfma_f32_16x16x32_bf16(af[m][ks], bf[ks], acc[m], 0, 0, 0);
        __syncthreads();
        buf ^= 1;
    }
#pragma unroll
    for (int m = 0; m < 4; ++m) {
        int col = wn * 16 + l15;
        int ng = n0 + col;
        int ocq = oc0 + wm * 64 + m * 16 + lq * 4;
        if (MODE == 0) {
            ushort4 o;
            float s0 = gamma[ocq >> 6] * 0.125f;
            o.x = f2bf((acc[m][0] + bias[ocq + 0]) * s0);
            o.y = f2bf((acc[m][1] + bias[ocq + 1]) * s0);
            o.z = f2bf((acc[m][2] + bias[ocq + 2]) * s0);
            o.w = f2bf((acc[m][3] + bias[ocq + 3]) * s0);
            *(ushort4*)&outp[((size_t)b * N2 + ng) * 256 + ocq] = o;
        } else {
#pragma unroll
            for (int r = 0; r < 4; ++r)
                outp[((size_t)(b * 256 + ocq + r)) * N2 + ng] = f2bf(acc[m][r] + bias[ocq + r]);
        }
    }
}

__global__ __launch_bounds__(256, 4) void kv_mfma(const float* __restrict__ kb_,
                                                  const float* __restrict__ vb_,
                                                  float* __restrict__ wsf) {
    int z = blockIdx.z, cv = z >> 1, b = z & 1;
    const ushort_t* wA  = (const ushort_t*)(wsf + (cv == 0 ? WV_OFF : WK_OFF));
    const ushort_t* xpm = (const ushort_t*)(wsf + (cv == 0 ? BUF0_OFF : BUF1_OFF));
    const float* bias   = cv == 0 ? vb_ : kb_;
    ushort_t* outp      = (ushort_t*)(wsf + (cv == 0 ? VC_OFF : KC_OFF));
    qkv_body<1>(blockIdx.x, blockIdx.y, b, bias, nullptr, wA, xpm, outp);
}

__global__ __launch_bounds__(256, 4) void q_mfma(const float* __restrict__ qb_,
                                                 const float* __restrict__ gamma,
                                                 float* __restrict__ wsf) {
    qkv_body<0>(blockIdx.x, blockIdx.y, blockIdx.z, qb_, gamma,
                (const ushort_t*)(wsf + WQ_OFF), (const ushort_t*)(wsf + BUF0_OFF),
                (ushort_t*)(wsf + QT_OFF));
}

// ---------------- S[d][d'] = sum_m v[d][m] k[d'][m]  (MFMA, atomic f32) ------
__global__ __launch_bounds__(64) void attn_S_mfma(float* __restrict__ wsf) {
    int mc = blockIdx.x, bh = blockIdx.y;
    int b = bh >> 2, h = bh & 3;
    const ushort_t* vp = (const ushort_t*)(wsf + VC_OFF) + (size_t)(b * 256 + h * 64) * N2;
    const ushort_t* kp = (const ushort_t*)(wsf + KC_OFF) + (size_t)(b * 256 + h * 64) * N2;
    float* Sp = wsf + S_OFF + (size_t)bh * 4096;
    int lane = threadIdx.x, l15 = lane & 15, lq = lane >> 4;
    f32x4 acc[4][4] = {};
    for (int m0 = mc * 128; m0 < mc * 128 + 128; m0 += 32) {
        short8 af[4], bf[4];
#pragma unroll
        for (int mt = 0; mt < 4; ++mt)
            af[mt] = *(const short8*)&vp[(size_t)(mt * 16 + l15) * N2 + m0 + lq * 8];
#pragma unroll
        for (int nt = 0; nt < 4; ++nt)
            bf[nt] = *(const short8*)&kp[(size_t)(nt * 16 + l15) * N2 + m0 + lq * 8];
#pragma unroll
        for (int mt = 0; mt < 4; ++mt)
#pragma unroll
            for (int nt = 0; nt < 4; ++nt)
                acc[mt][nt] = __builtin_amdgcn_mfma_f32_16x16x32_bf16(
                    af[mt], bf[nt], acc[mt][nt], 0, 0, 0);
    }
#pragma unroll
    for (int mt = 0; mt < 4; ++mt)
#pragma unroll
        for (int nt = 0; nt < 4; ++nt)
#pragma unroll
            for (int r = 0; r < 4; ++r)
                atomicAdd(&Sp[(mt * 16 + lq * 4 + r) * 64 + nt * 16 + l15], acc[mt][nt][r]);
}

// ---------------- M[b][oc][h*64+d''] = sum_d W_att[oc][h*64+d] S_bh[d][d''] ----
// grid 8 (b*4+h), block 256 (4 waves: wave wv -> oc rows wv*64..). K=64.
__global__ __launch_bounds__(256) void attn_M_mfma(float* __restrict__ wsf) {
    int bh = blockIdx.x;
    int b = bh >> 2, h = bh & 3;
    const float* Sp = wsf + S_OFF + (size_t)bh * 4096;
    const ushort_t* wF = (const ushort_t*)(wsf + WF_OFF);
    ushort_t* M = (ushort_t*)(wsf + M_OFF);
    __shared__ ushort_t SlT[64][72];   // S transposed: SlT[d''][d]
    int t = threadIdx.x;
#pragma unroll
    for (int g = 0; g < 4; ++g) {
        int idx = t * 16 + g * 4;
        float4 v = *(const float4*)&Sp[idx];   // S[d][d''], d=idx>>6, d''=idx&63..+3
        int d = idx >> 6, dd = idx & 63;
        SlT[dd + 0][d] = f2bf(v.x);
        SlT[dd + 1][d] = f2bf(v.y);
        SlT[dd + 2][d] = f2bf(v.z);
        SlT[dd + 3][d] = f2bf(v.w);
    }
    __syncthreads();
    int lane = t & 63, wv = t >> 6, l15 = lane & 15, lq = lane >> 4;
    f32x4 acc[4][4] = {};
#pragma unroll
    for (int ks = 0; ks < 2; ++ks) {
        short8 aw[4], bs[4];
#pragma unroll
        for (int mt = 0; mt < 4; ++mt) {
            int oc = wv * 64 + mt * 16 + l15;
            aw[mt] = *(const short8*)&wF[(size_t)oc * 512 + 256 + h * 64 + ks * 32 + lq * 8];
        }
#pragma unroll
        for (int nt = 0; nt < 4; ++nt)
            bs[nt] = *(const short8*)&SlT[nt * 16 + l15][ks * 32 + lq * 8];
#pragma unroll
        for (int mt = 0; mt < 4; ++mt)
#pragma unroll
            for (int nt = 0; nt < 4; ++nt)
                acc[mt][nt] = __builtin_amdgcn_mfma_f32_16x16x32_bf16(
                    aw[mt], bs[nt], acc[mt][nt], 0, 0, 0);
    }
#pragma unroll
    for (int mt = 0; mt < 4; ++mt)
#pragma unroll
        for (int nt = 0; nt < 4; ++nt) {
            int dd = nt * 16 + l15;
#pragma unroll
            for (int r = 0; r < 4; ++r) {
                int oc = wv * 64 + mt * 16 + lq * 4 + r;
                M[((size_t)b * 256 + oc) * 256 + h * 64 + dd] = f2bf(acc[mt][nt][r]);
            }
        }
}

// ---------------- 1x1 conv MFMA (BN=64, dbuf) -> xcatT pixel-major ----------
// K=512: c<256 pose (A=wF, B=xpm); c>=256 folded-attn (A=M_b, B=qT half-res).
__global__ __launch_bounds__(256, 3) void conv1x1_mfma(const float* __restrict__ fb,
                                                       float* __restrict__ wsf) {
    int lin = blockIdx.x;
    int swz = (lin & 7) * 128 + (lin >> 3);
    int xh = swz & 1, y = (swz >> 1) & 127, oct = (swz >> 8) & 1, b = swz >> 9;
    int oc0 = oct * 128, x0 = xh * 64;
    const ushort_t* wF   = (const ushort_t*)(wsf + WF_OFF);
    const ushort_t* Mb   = (const ushort_t*)(wsf + M_OFF) + (size_t)b * 65536;
    const ushort_t* xpm  = (const ushort_t*)(wsf + BUF0_OFF);   // pose pixel-major
    const ushort_t* qT   = (const ushort_t*)(wsf + QT_OFF);
    ushort_t* xcatT      = (ushort_t*)(wsf + XCAT_OFF);

    __shared__ alignas(16) ushort_t As[2][128 * 64];
    __shared__ alignas(16) ushort_t Bs[2][64 * 64];
    int t = threadIdx.x, lane = t & 63, wv = t >> 6;
    int wm = wv >> 1, wn = wv & 1, l15 = lane & 15, lq = lane >> 4;
    f32x4 acc[4][2] = {};

    auto stage = [&](int chunk, int bufi) {
        int c0 = chunk << 6;
#pragma unroll
        for (int r = 0; r < 4; ++r) {
            int slot = t + r * 256;
            int row = slot >> 3, cbk = slot & 7;
            int sw = (cbk ^ (row & 7)) << 3;
            const ushort_t* src;
            if (c0 < 256) src = wF + ((size_t)(oc0 + row) * 512 + c0 + sw);
            else          src = Mb + ((size_t)(oc0 + row) * 256 + (c0 - 256) + sw);
            gload_lds16(src, (ushort_t*)As[bufi] + (((size_t)wv * 64 + r * 256) << 3));
        }
#pragma unroll
        for (int r = 0; r < 2; ++r) {
            int slot = t + r * 256;
            int n = slot >> 3, cbk = slot & 7;
            int x = x0 + n;
            int sw = (cbk ^ (n & 7)) << 3;
            const ushort_t* src;
            if (c0 < 256)
                src = xpm + (((size_t)b * HWP + (size_t)y * 128 + x) * 256 + c0 + sw);
            else
                src = qT + (((size_t)b * N2 + (size_t)(y >> 1) * 64 + (x >> 1)) * 256
                            + (c0 - 256) + sw);
            gload_lds16(src, (ushort_t*)Bs[bufi] + (((size_t)wv * 64 + r * 256) << 3));
        }
    };

    stage(0, 0);
    __syncthreads();
    int buf = 0;
    for (int chunk = 0; chunk < 8; ++chunk) {
        short8 af[4][2], bf[2][2];
#pragma unroll
        for (int m = 0; m < 4; ++m) {
            int row = wm * 64 + m * 16 + l15;
#pragma unroll
            for (int ks = 0; ks < 2; ++ks)
                af[m][ks] = *(const short8*)&As[buf][row * 64 + (((ks * 4 + lq) ^ (row & 7)) << 3)];
        }
#pragma unroll
        for (int n = 0; n < 2; ++n) {
            int col = wn * 32 + n * 16 + l15;
#pragma unroll
            for (int ks = 0; ks < 2; ++ks)
                bf[n][ks] = *(const short8*)&Bs[buf][col * 64 + (((ks * 4 + lq) ^ (col & 7)) << 3)];
        }
        if (chunk < 7) stage(chunk + 1, buf ^ 1);
#pragma unroll
        for (int ks = 0; ks < 2; ++ks)
#pragma unroll
            for (int m = 0; m < 4; ++m)
#pragma unroll
                for (int n = 0; n < 2; ++n)
                    acc[m][n] = __builtin_amdgcn_mfma_f32_16x16x32_bf16(
                        af[m][ks], bf[n][ks], acc[m][n], 0, 0, 0);
        __syncthreads();
        buf ^= 1;
    }
#pragma unroll
    for (int m = 0; m < 4; ++m)
#pragma unroll
        for (int n = 0; n < 2; ++n) {
            int col = x0 + wn * 32 + n * 16 + l15;
            int ocq = oc0 + wm * 64 + m * 16 + lq * 4;
            ushort4 o;
            o.x = f2bf(acc[m][n][0] + fb[ocq + 0]);
            o.y = f2bf(acc[m][n][1] + fb[ocq + 1]);
            o.z = f2bf(acc[m][n][2] + fb[ocq + 2]);
            o.w = f2bf(acc[m][n][3] + fb[ocq + 3]);
            *(ushort4*)&xcatT[((size_t)b * HWP + (size_t)y * 128 + col) * 256 + ocq] = o;
        }
}

// ---------------- 3x3 SAME conv: R13 structure + fused IN sums ----------------
__global__ __launch_bounds__(256, 2) void conv3x3_mfma(const float* __restrict__ cb,
                                                       float* __restrict__ wsf) {
    int lin = blockIdx.x;
    int swz = (lin & 7) * 64 + (lin >> 3);   // XCD-contiguous
    int y = swz & 127, oct = (swz >> 7) & 1, b = swz >> 8;
    int oc0 = oct * 128;
    int py = y & 1, yh = y >> 1;

    const ushort_t* xcatT = (const ushort_t*)(wsf + XCAT_OFF);
    const ushort_t* prevT = (const ushort_t*)(wsf + PREVT_OFF);
    const ushort_t* wA3x  = (const ushort_t*)(wsf + WA3X_OFF);
    const ushort_t* wPP   = (const ushort_t*)(wsf + WPP_OFF);
    const ushort_t* zp    = (const ushort_t*)(wsf + ZP_OFF);
    ushort_t* y3          = (ushort_t*)(wsf + Y3_OFF);

    __shared__ alignas(16) ushort_t As[2 * 128 * 64];   // 32 KB (2 parity variants for prev)
    __shared__ alignas(16) ushort_t Bs[128 * 64];       // 16 KB
    int t = threadIdx.x, lane = t & 63, wv = t >> 6;
    int wm = wv >> 1, wn = wv & 1, l15 = lane & 15, lq = lane >> 4;
    f32x4 acc[4][4] = {};

    for (int chunk = 0; chunk < 52; ++chunk) {
        bool isPrev = chunk >= 36;
        if (!isPrev) {
            int tap = chunk >> 2, c0 = (chunk & 3) << 6;
            int fy = tap / 3, fx = tap - fy * 3;
            int yy = y + fy - 1;
#pragma unroll
            for (int r = 0; r < 4; ++r) {      // A: xcat weights [128 oc][64 c]
                int slot = t + r * 256;
                int row = slot >> 3, cbk = slot & 7;
                const ushort_t* src = wA3x + (((size_t)tap * 256 + oc0 + row) * 256
                                              + c0 + ((cbk ^ (row & 7)) << 3));
                gload_lds16(src, (ushort_t*)As + (((size_t)wv * 64 + r * 256) << 3));
            }
#pragma unroll
            for (int r = 0; r < 4; ++r) {      // B: xcat pixels (permuted x), zero page OOB
                int slot = t + r * 256;
                int n = slot >> 3, cbk = slot & 7;
                int x = 2 * (n & 63) + (n >> 6);
                int xx = x + fx - 1;
                int sw = (cbk ^ (n & 7)) << 3;
                bool ok = (yy >= 0) && (yy < 128) && (xx >= 0) && (xx < 128);
                const ushort_t* src = ok
                    ? xcatT + (((size_t)b * HWP + (size_t)yy * 128 + xx) * 256 + c0 + sw)
                    : zp;
                gload_lds16(src, (ushort_t*)Bs + (((size_t)wv * 64 + r * 256) << 3));
            }
        } else {
            int pi = chunk - 36;
            int tap4 = pi >> 2, c0 = (pi & 3) << 6;   // tap4 = j2*2 + i2
            int j2 = tap4 >> 1, i2 = tap4 & 1;
            int pr = yh + py + j2 - 1;
#pragma unroll
            for (int r = 0; r < 8; ++r) {      // A: BOTH col-parity weight variants
                int slot = t + r * 256;
                int p = slot >> 10, rem = slot & 1023;
                int row = rem >> 3, cbk = rem & 7;
                const ushort_t* src = wPP + (((size_t)((py * 2 + p) * 4 + tap4) * 256
                                              + oc0 + row) * 256 + c0 + ((cbk ^ (row & 7)) << 3));
                gload_lds16(src, (ushort_t*)As + (((size_t)wv * 64 + r * 256) << 3));
            }
#pragma unroll
            for (int r = 0; r < 4; ++r) {      // B: prev pixels (permuted x), zero page OOB
                int slot = t + r * 256;
                int n = slot >> 3, cbk = slot & 7;
                int pc = (n & 63) - 1 + i2 + (n >> 6);
                int sw = (cbk ^ (n & 7)) << 3;
                bool ok = (pr >= 0) && (pr < 64) && (pc >= 0) && (pc < 64);
                const ushort_t* src = ok
                    ? prevT + (((size_t)b * N2 + (size_t)pr * 64 + pc) * 256 + c0 + sw)
                    : zp;
                gload_lds16(src, (ushort_t*)Bs + (((size_t)wv * 64 + r * 256) << 3));
            }
        }
        __syncthreads();   // drains vmcnt -> LDS tiles ready
        int abase = isPrev ? wn * 8192 : 0;    // prev: wave's col-parity variant
#pragma unroll
        for (int ks = 0; ks < 2; ++ks) {
            short8 af[4], bf[4];
#pragma unroll
            for (int m = 0; m < 4; ++m) {
                int row = wm * 64 + m * 16 + l15;
                af[m] = *(const short8*)&As[abase + row * 64 + (((ks * 4 + lq) ^ (row & 7)) << 3)];
            }
#pragma unroll
            for (int n = 0; n < 4; ++n) {
                int col = wn * 64 + n * 16 + l15;
                bf[n] = *(const short8*)&Bs[col * 64 + (((ks * 4 + lq) ^ (col & 7)) << 3)];
            }
#pragma unroll
            for (int m = 0; m < 4; ++m)
#pragma unroll
                for (int n = 0; n < 4; ++n)
                    acc[m][n] = __builtin_amdgcn_mfma_f32_16x16x32_bf16(
                        af[m], bf[n], acc[m][n], 0, 0, 0);
        }
        __syncthreads();   // all reads done before next stage overwrites
    }

    // epilogue: bias + bf16 store (permuted col -> x) + fused IN partial sums
    float* SUM  = wsf + SUM_OFF;
    float* SUM2 = wsf + SUM2_OFF;
#pragma unroll
    for (int m = 0; m < 4; ++m)
#pragma unroll
        for (int r = 0; r < 4; ++r) {
            int oc = oc0 + wm * 64 + m * 16 + lq * 4 + r;
            float bv = cb[oc];
            float s1 = 0.f, s2 = 0.f;
#pragma unroll
            for (int n = 0; n < 4; ++n) {
                float v = acc[m][n][r] + bv;
                s1 += v; s2 += v * v;
                int col = wn * 64 + n * 16 + l15;
                int x = 2 * (col & 63) + (col >> 6);
                y3[((size_t)b * 256 + oc) * HWP + (size_t)y * 128 + x] = f2bf(v);
            }
#pragma unroll
            for (int o2 = 1; o2 < 16; o2 <<= 1) {
                s1 += __shfl_xor(s1, o2, 64);
                s2 += __shfl_xor(s2, o2, 64);
            }
            if (l15 == 0) {
                atomicAdd(&SUM[b * 256 + oc], s1);
                atomicAdd(&SUM2[b * 256 + oc], s2);
            }
        }
}

// ---------------- instance norm + relu (single pass, sums from conv3x3) ------
__global__ __launch_bounds__(256) void inorm_relu_k(const float* __restrict__ wsf,
                                                    float* __restrict__ out) {
    int bc = blockIdx.x;   // b*256+oc
    const ushort_t* yp = (const ushort_t*)(wsf + Y3_OFF) + (size_t)bc * HWP;
    float mean = wsf[SUM_OFF + bc] * (1.f / HWP);
    float var  = wsf[SUM2_OFF + bc] * (1.f / HWP) - mean * mean;
    float inv  = rsqrtf(var + EPSI);
    float* op = out + (size_t)bc * HWP;
    int t = threadIdx.x;
#pragma unroll
    for (int i = 0; i < 8; ++i) {
        int base = (t + i * 256) * 8;
        short8 v = *(const short8*)&yp[(size_t)base];
        float4 o0, o1;
        o0.x = fmaxf((bf2f((ushort_t)v[0]) - mean) * inv, 0.f);
        o0.y = fmaxf((bf2f((ushort_t)v[1]) - mean) * inv, 0.f);
        o0.z = fmaxf((bf2f((ushort_t)v[2]) - mean) * inv, 0.f);
        o0.w = fmaxf((bf2f((ushort_t)v[3]) - mean) * inv, 0.f);
        o1.x = fmaxf((bf2f((ushort_t)v[4]) - mean) * inv, 0.f);
        o1.y = fmaxf((bf2f((ushort_t)v[5]) - mean) * inv, 0.f);
        o1.z = fmaxf((bf2f((ushort_t)v[6]) - mean) * inv, 0.f);
        o1.w = fmaxf((bf2f((ushort_t)v[7]) - mean) * inv, 0.f);
        *(float4*)&op[base]     = o0;
        *(float4*)&op[base + 4] = o1;
    }
}

extern "C" void kernel_launch(void* const* d_in, const int* in_sizes, int n_in,
                              void* d_out, int out_size, void* d_ws, size_t ws_size,
                              hipStream_t stream)
{
    (void)in_sizes; (void)n_in; (void)out_size; (void)ws_size;
    const float* app_enc  = (const float*)d_in[0];
    const float* app_pose = (const float*)d_in[1];
    const float* pose_enc = (const float*)d_in[2];
    const float* prev_inp = (const float*)d_in[3];
    const float* qw = (const float*)d_in[4];
    const float* qb = (const float*)d_in[5];
    const float* kw = (const float*)d_in[6];
    const float* kb = (const float*)d_in[7];
    const float* vw = (const float*)d_in[8];
    const float* vb = (const float*)d_in[9];
    const float* gamma = (const float*)d_in[10];
    const float* fw = (const float*)d_in[11];
    const float* fb = (const float*)d_in[12];
    const float* cw = (const float*)d_in[13];
    const float* cb = (const float*)d_in[14];
    float* ws  = (float*)d_ws;
    float* out = (float*)d_out;

    // 1. weight packs + prevT + zero-init
    prep_k<<<dim3(512, 7), 256, 0, stream>>>(qw, kw, vw, fw, cw, prev_inp, ws);
    // 2. app_enc -> BUF0, app_pose -> BUF1
    xpm2_k<<<dim3(128, 4, 4), 256, 0, stream>>>(app_enc, app_pose, ws);
    // 3. v (BUF0) and k (BUF1) projections, merged
    kv_mfma<<<dim3(128, 2, 4), 256, 0, stream>>>(kb, vb, ws);
    // 4. S = v k^T (256 blocks)
    attn_S_mfma<<<dim3(32, 8), 64, 0, stream>>>(ws);
    // 5. pose -> BUF0
    xpmP_k<<<dim3(128, 4, 2), 256, 0, stream>>>(pose_enc, ws);
    // 6. q projection (gamma/8 folded, pixel-major)
    q_mfma<<<dim3(128, 2, 2), 256, 0, stream>>>(qb, gamma, ws);
    // 7. M = W_att x S (replaces attn_O; writes into dead k region)
    attn_M_mfma<<<8, 256, 0, stream>>>(ws);
    // 8. 1x1 conv: pose half + folded-attn half (M x qT) -> xcatT
    conv1x1_mfma<<<1024, 256, 0, stream>>>(fb, ws);
    // 9. 3x3 conv: 52 chunks + fused IN sums -> y3 (BUF1)
    conv3x3_mfma<<<512, 256, 0, stream>>>(cb, ws);
    // 10. instance norm + relu (single pass) -> f32 out
    inorm_relu_k<<<512, 256, 0, stream>>>(ws, out);
}

// Round 15
// 180.512 us; speedup vs baseline: 1.1385x; 1.1385x over previous
//
#include <hip/hip_runtime.h>
#include <hip/hip_bf16.h>

#define N2   4096    // 64*64 attn pixels
#define HWP  16384   // 128*128
#define EPSI 1e-5f

typedef unsigned short ushort_t;
typedef __attribute__((ext_vector_type(8))) short short8;
typedef __attribute__((ext_vector_type(4))) float f32x4;

// ---- workspace layout (f32-word offsets), peak 18,089,024 words = 72.4 MB ----
static const size_t BUF0_OFF  = 0;          // bf16 [2][16384][256]
static const size_t BUF1_OFF  = 4194304;    // bf16 [2][16384][256]  (later y3)
static const size_t QT_OFF    = 8388608;    // bf16 [2][4096][256]  q pixel-major (gamma/8 folded)
static const size_t KC_OFF    = 9437184;    // bf16 [2][256][4096]  k channel-major; later M[2][256][256]
static const size_t VC_OFF    = 10485760;   // bf16 [2][256][4096]
static const size_t S_OFF     = 11534336;   // f32 [8][64][64]   --- zero region start
static const size_t SUM_OFF   = 11567104;   // f32 [512] (unused)
static const size_t SUM2_OFF  = 11567616;   // f32 [512] (unused)
static const size_t ZP_OFF    = 11568128;   // f32 [64] zero page --- zero region end (33,856)
static const size_t XCAT_OFF  = 11568192;   // bf16 [2][16384][256] conv1x1 out pixel-major
static const size_t PREVT_OFF = 15762496;   // bf16 [2][4096][256]  prev pixel-major (unpadded)
static const size_t WQ_OFF    = 16811072;   // bf16 [4][256][256]
static const size_t WK_OFF    = 16942144;
static const size_t WV_OFF    = 17073216;
static const size_t WF_OFF    = 17204288;   // bf16 [256][512]
static const size_t WA3X_OFF  = 17269824;   // bf16 [9][256][256]  3x3 weights, xcat channels
static const size_t WPP_OFF   = 17564736;   // bf16 [16][256][256] row+col-collapsed prev weights
static const size_t Y3_OFF    = BUF1_OFF;
static const size_t M_OFF     = KC_OFF;     // bf16 [2][256][256] = W_att x S (aliases dead k)

__device__ __forceinline__ ushort_t f2bf(float x) {
    union { float f; unsigned u; } v; v.f = x;
    unsigned r = v.u + 0x7FFFu + ((v.u >> 16) & 1u);
    return (ushort_t)(r >> 16);
}
__device__ __forceinline__ float bf2f(ushort_t h) {
    union { unsigned u; float f; } v; v.u = ((unsigned)h) << 16; return v.f;
}
__device__ __forceinline__ void gload_lds16(const void* g, void* l) {
    __builtin_amdgcn_global_load_lds(
        (const __attribute__((address_space(1))) void*)g,
        (__attribute__((address_space(3))) void*)l, 16, 0, 0);
}

// ---------------- prep: weight packs + prevT + zero-init ----------------
__global__ __launch_bounds__(256) void prep_k(const float* __restrict__ qw,
                                              const float* __restrict__ kw,
                                              const float* __restrict__ vw,
                                              const float* __restrict__ fw,
                                              const float* __restrict__ cw,
                                              const float* __restrict__ prev,
                                              float* __restrict__ wsf) {
    __shared__ ushort_t T[64][64];
    int sec = blockIdx.y, bx = blockIdx.x, t = threadIdx.x;
    if (sec < 3) {               // pack q/k/v weights: [oc][c][2][2] -> wA[tap][oc][c]
        if (bx >= 256) return;
        int idx = bx * 256 + t;
        const float* src = sec == 0 ? qw : (sec == 1 ? kw : vw);
        ushort_t* dst = (ushort_t*)(wsf + (sec == 0 ? WQ_OFF : (sec == 1 ? WK_OFF : WV_OFF)));
        float4 v = *(const float4*)&src[(size_t)idx * 4];
        dst[0 * 65536 + idx] = f2bf(v.x);
        dst[1 * 65536 + idx] = f2bf(v.y);
        dst[2 * 65536 + idx] = f2bf(v.z);
        dst[3 * 65536 + idx] = f2bf(v.w);
    } else if (sec == 3) {       // pack fw
        int idx = bx * 256 + t;
        ((ushort_t*)(wsf + WF_OFF))[idx] = f2bf(fw[idx]);
    } else if (sec == 4) {       // pack 3x3 weights: xcat taps + row+col-collapsed prev taps
        int idx = bx * 256 + t;  // oc*512 + c
        int oc = idx >> 9, c = idx & 511;
        const float* src = cw + (size_t)idx * 9;
        float w[9];
#pragma unroll
        for (int tp = 0; tp < 9; ++tp) w[tp] = src[tp];
        if (c < 256) {
            ushort_t* wA3x = (ushort_t*)(wsf + WA3X_OFF);
#pragma unroll
            for (int tp = 0; tp < 9; ++tp)
                wA3x[((size_t)tp * 256 + oc) * 256 + c] = f2bf(w[tp]);
        } else {
            int cc = c - 256;
            ushort_t* wPP = (ushort_t*)(wsf + WPP_OFF);
#pragma unroll
            for (int py = 0; py < 2; ++py) {
                float rs[2][3];
#pragma unroll
                for (int fx = 0; fx < 3; ++fx) {
                    if (py == 0) { rs[0][fx] = w[fx];           rs[1][fx] = w[3 + fx] + w[6 + fx]; }
                    else         { rs[0][fx] = w[fx] + w[3 + fx]; rs[1][fx] = w[6 + fx]; }
                }
#pragma unroll
                for (int pxp = 0; pxp < 2; ++pxp)
#pragma unroll
                    for (int j2 = 0; j2 < 2; ++j2) {
                        float v0 = pxp == 0 ? rs[j2][0] : rs[j2][0] + rs[j2][1];
                        float v1 = pxp == 0 ? rs[j2][1] + rs[j2][2] : rs[j2][2];
                        wPP[(((size_t)((py * 2 + pxp) * 4 + j2 * 2 + 0)) * 256 + oc) * 256 + cc] = f2bf(v0);
                        wPP[(((size_t)((py * 2 + pxp) * 4 + j2 * 2 + 1)) * 256 + oc) * 256 + cc] = f2bf(v1);
                    }
            }
        }
    } else if (sec == 5) {       // prevT: [b][256][64][64] -> [b][4096][256] (unpadded)
        int y2 = bx & 63, ct = (bx >> 6) & 3, b = bx >> 8;
        ushort_t* pT = (ushort_t*)(wsf + PREVT_OFF);
#pragma unroll
        for (int i = 0; i < 4; ++i) {
            int s = t + i * 256;
            int cc = s >> 4, xq = s & 15;
            float4 v = *(const float4*)&prev[(((size_t)b * 256 + ct * 64 + cc) * 64 + y2) * 64 + xq * 4];
            ushort4 h; h.x = f2bf(v.x); h.y = f2bf(v.y); h.z = f2bf(v.z); h.w = f2bf(v.w);
            *(ushort4*)&T[cc][xq * 4] = h;
        }
        __syncthreads();
#pragma unroll
        for (int i = 0; i < 2; ++i) {
            int w = t * 2 + i;
            int px = w >> 3, cbk = w & 7;
            short8 o;
#pragma unroll
            for (int j = 0; j < 8; ++j) o[j] = (short)T[cbk * 8 + j][px];
            *(short8*)&pT[((size_t)b * N2 + (size_t)y2 * 64 + px) * 256 + ct * 64 + cbk * 8] = o;
        }
    } else {                     // zero S/SUM/SUM2/ZP
        int idx = bx * 256 + t;
        if (idx < 33856) wsf[S_OFF + idx] = 0.f;
    }
}

// ---------------- input -> pixel-major bf16 ----------------
__device__ __forceinline__ void xpm_body(const float* __restrict__ in, ushort_t* __restrict__ xpm,
                                         int y, int ct, int b, int t) {
    __shared__ ushort_t T[64][128];
#pragma unroll
    for (int i = 0; i < 8; ++i) {
        int s = t + i * 256;
        int cc = s >> 5, xq = s & 31;
        float4 v = *(const float4*)&in[(((size_t)b * 256 + ct * 64 + cc) * 128 + y) * 128 + xq * 4];
        ushort4 h; h.x = f2bf(v.x); h.y = f2bf(v.y); h.z = f2bf(v.z); h.w = f2bf(v.w);
        *(ushort4*)&T[cc][xq * 4] = h;
    }
    __syncthreads();
#pragma unroll
    for (int i = 0; i < 4; ++i) {
        int w = t * 4 + i;
        int px = w >> 3, cbk = w & 7;
        short8 o;
#pragma unroll
        for (int j = 0; j < 8; ++j) o[j] = (short)T[cbk * 8 + j][px];
        *(short8*)&xpm[(((size_t)b * HWP) + (size_t)y * 128 + px) * 256 + ct * 64 + cbk * 8] = o;
    }
}

__global__ __launch_bounds__(256) void xpm2_k(const float* __restrict__ app,
                                              const float* __restrict__ app_pose,
                                              float* __restrict__ wsf) {
    int z = blockIdx.z, which = z >> 1, b = z & 1;
    const float* in = which == 0 ? app : app_pose;
    ushort_t* dst = (ushort_t*)(wsf + (which == 0 ? BUF0_OFF : BUF1_OFF));
    xpm_body(in, dst, blockIdx.x, blockIdx.y, b, threadIdx.x);
}

__global__ __launch_bounds__(256) void xpmP_k(const float* __restrict__ pose,
                                              float* __restrict__ wsf) {
    xpm_body(pose, (ushort_t*)(wsf + BUF0_OFF), blockIdx.x, blockIdx.y, blockIdx.z, threadIdx.x);
}

// ---------------- qkv stride-2 2x2 conv GEMM body ----------------
template<int MODE>
__device__ __forceinline__ void qkv_body(int nb, int oct, int b,
                                         const float* __restrict__ bias,
                                         const float* __restrict__ gamma,
                                         const ushort_t* __restrict__ wA,
                                         const ushort_t* __restrict__ xpm,
                                         ushort_t* __restrict__ outp) {
    int n0 = nb * 32, oc0 = oct * 128;
    __shared__ alignas(16) ushort_t As[2][128 * 64];
    __shared__ alignas(16) ushort_t Bs[2][32 * 64];
    int t = threadIdx.x, lane = t & 63, wv = t >> 6;
    int wm = wv >> 1, wn = wv & 1, l15 = lane & 15, lq = lane >> 4;
    f32x4 acc[4] = {};

    auto stage = [&](int chunk, int bufi) {
        int tap = chunk >> 2, c0 = (chunk & 3) << 6;
        int fy = tap >> 1, fx = tap & 1;
#pragma unroll
        for (int r = 0; r < 4; ++r) {
            int slot = t + r * 256;
            int row = slot >> 3, cbk = slot & 7;
            const ushort_t* src = wA + ((size_t)tap * 65536 + (size_t)(oc0 + row) * 256
                                        + c0 + ((cbk ^ (row & 7)) << 3));
            gload_lds16(src, (ushort_t*)As[bufi] + (((size_t)wv * 64 + r * 256) << 3));
        }
        {
            int n = t >> 3, cbk = t & 7;
            int ng = n0 + n;
            int iy = ((ng >> 6) << 1) + fy, ix = ((ng & 63) << 1) + fx;
            const ushort_t* src = xpm + (((size_t)b * HWP + (size_t)iy * 128 + ix) * 256
                                         + c0 + ((cbk ^ (n & 7)) << 3));
            gload_lds16(src, (ushort_t*)Bs[bufi] + ((size_t)wv * 64 << 3));
        }
    };

    stage(0, 0);
    __syncthreads();
    int buf = 0;
    for (int chunk = 0; chunk < 16; ++chunk) {
        short8 af[4][2], bf[2];
#pragma unroll
        for (int m = 0; m < 4; ++m) {
            int row = wm * 64 + m * 16 + l15;
#pragma unroll
            for (int ks = 0; ks < 2; ++ks)
                af[m][ks] = *(const short8*)&As[buf][row * 64 + (((ks * 4 + lq) ^ (row & 7)) << 3)];
        }
        {
            int col = wn * 16 + l15;
#pragma unroll
            for (int ks = 0; ks < 2; ++ks)
                bf[ks] = *(const short8*)&Bs[buf][col * 64 + (((ks * 4 + lq) ^ (col & 7)) << 3)];
        }
        if (chunk < 15) stage(chunk + 1, buf ^ 1);
#pragma unroll
        for (int ks = 0; ks < 2; ++ks)
#pragma unroll
            for (int m = 0; m < 4; ++m)
                acc[m] = __builtin_amdgcn_mfma_f32_16x16x32_bf16(af[m][ks], bf[ks], acc[m], 0, 0, 0);
        __syncthreads();
        buf ^= 1;
    }
#pragma unroll
    for (int m = 0; m < 4; ++m) {
        int col = wn * 16 + l15;
        int ng = n0 + col;
        int ocq = oc0 + wm * 64 + m * 16 + lq * 4;
        if (MODE == 0) {
            ushort4 o;
            float s0 = gamma[ocq >> 6] * 0.125f;
            o.x = f2bf((acc[m][0] + bias[ocq + 0]) * s0);
            o.y = f2bf((acc[m][1] + bias[ocq + 1]) * s0);
            o.z = f2bf((acc[m][2] + bias[ocq + 2]) * s0);
            o.w = f2bf((acc[m][3] + bias[ocq + 3]) * s0);
            *(ushort4*)&outp[((size_t)b * N2 + ng) * 256 + ocq] = o;
        } else {
#pragma unroll
            for (int r = 0; r < 4; ++r)
                outp[((size_t)(b * 256 + ocq + r)) * N2 + ng] = f2bf(acc[m][r] + bias[ocq + r]);
        }
    }
}

__global__ __launch_bounds__(256, 4) void kv_mfma(const float* __restrict__ kb_,
                                                  const float* __restrict__ vb_,
                                                  float* __restrict__ wsf) {
    int z = blockIdx.z, cv = z >> 1, b = z & 1;
    const ushort_t* wA  = (const ushort_t*)(wsf + (cv == 0 ? WV_OFF : WK_OFF));
    const ushort_t* xpm = (const ushort_t*)(wsf + (cv == 0 ? BUF0_OFF : BUF1_OFF));
    const float* bias   = cv == 0 ? vb_ : kb_;
    ushort_t* outp      = (ushort_t*)(wsf + (cv == 0 ? VC_OFF : KC_OFF));
    qkv_body<1>(blockIdx.x, blockIdx.y, b, bias, nullptr, wA, xpm, outp);
}

__global__ __launch_bounds__(256, 4) void q_mfma(const float* __restrict__ qb_,
                                                 const float* __restrict__ gamma,
                                                 float* __restrict__ wsf) {
    qkv_body<0>(blockIdx.x, blockIdx.y, blockIdx.z, qb_, gamma,
                (const ushort_t*)(wsf + WQ_OFF), (const ushort_t*)(wsf + BUF0_OFF),
                (ushort_t*)(wsf + QT_OFF));
}

// ---------------- S[d][d'] = sum_m v[d][m] k[d'][m]  (MFMA, atomic f32) ------
__global__ __launch_bounds__(64) void attn_S_mfma(float* __restrict__ wsf) {
    int mc = blockIdx.x, bh = blockIdx.y;
    int b = bh >> 2, h = bh & 3;
    const ushort_t* vp = (const ushort_t*)(wsf + VC_OFF) + (size_t)(b * 256 + h * 64) * N2;
    const ushort_t* kp = (const ushort_t*)(wsf + KC_OFF) + (size_t)(b * 256 + h * 64) * N2;
    float* Sp = wsf + S_OFF + (size_t)bh * 4096;
    int lane = threadIdx.x, l15 = lane & 15, lq = lane >> 4;
    f32x4 acc[4][4] = {};
    for (int m0 = mc * 128; m0 < mc * 128 + 128; m0 += 32) {
        short8 af[4], bf[4];
#pragma unroll
        for (int mt = 0; mt < 4; ++mt)
            af[mt] = *(const short8*)&vp[(size_t)(mt * 16 + l15) * N2 + m0 + lq * 8];
#pragma unroll
        for (int nt = 0; nt < 4; ++nt)
            bf[nt] = *(const short8*)&kp[(size_t)(nt * 16 + l15) * N2 + m0 + lq * 8];
#pragma unroll
        for (int mt = 0; mt < 4; ++mt)
#pragma unroll
            for (int nt = 0; nt < 4; ++nt)
                acc[mt][nt] = __builtin_amdgcn_mfma_f32_16x16x32_bf16(
                    af[mt], bf[nt], acc[mt][nt], 0, 0, 0);
    }
#pragma unroll
    for (int mt = 0; mt < 4; ++mt)
#pragma unroll
        for (int nt = 0; nt < 4; ++nt)
#pragma unroll
            for (int r = 0; r < 4; ++r)
                atomicAdd(&Sp[(mt * 16 + lq * 4 + r) * 64 + nt * 16 + l15], acc[mt][nt][r]);
}

// ---------------- M[b][oc][h*64+d''] = sum_d W_att[oc][h*64+d] S_bh[d][d''] ----
__global__ __launch_bounds__(256) void attn_M_mfma(float* __restrict__ wsf) {
    int bh = blockIdx.x;
    int b = bh >> 2, h = bh & 3;
    const float* Sp = wsf + S_OFF + (size_t)bh * 4096;
    const ushort_t* wF = (const ushort_t*)(wsf + WF_OFF);
    ushort_t* M = (ushort_t*)(wsf + M_OFF);
    __shared__ ushort_t SlT[64][72];   // S transposed: SlT[d''][d]
    int t = threadIdx.x;
#pragma unroll
    for (int g = 0; g < 4; ++g) {
        int idx = t * 16 + g * 4;
        float4 v = *(const float4*)&Sp[idx];
        int d = idx >> 6, dd = idx & 63;
        SlT[dd + 0][d] = f2bf(v.x);
        SlT[dd + 1][d] = f2bf(v.y);
        SlT[dd + 2][d] = f2bf(v.z);
        SlT[dd + 3][d] = f2bf(v.w);
    }
    __syncthreads();
    int lane = t & 63, wv = t >> 6, l15 = lane & 15, lq = lane >> 4;
    f32x4 acc[4][4] = {};
#pragma unroll
    for (int ks = 0; ks < 2; ++ks) {
        short8 aw[4], bs[4];
#pragma unroll
        for (int mt = 0; mt < 4; ++mt) {
            int oc = wv * 64 + mt * 16 + l15;
            aw[mt] = *(const short8*)&wF[(size_t)oc * 512 + 256 + h * 64 + ks * 32 + lq * 8];
        }
#pragma unroll
        for (int nt = 0; nt < 4; ++nt)
            bs[nt] = *(const short8*)&SlT[nt * 16 + l15][ks * 32 + lq * 8];
#pragma unroll
        for (int mt = 0; mt < 4; ++mt)
#pragma unroll
            for (int nt = 0; nt < 4; ++nt)
                acc[mt][nt] = __builtin_amdgcn_mfma_f32_16x16x32_bf16(
                    aw[mt], bs[nt], acc[mt][nt], 0, 0, 0);
    }
#pragma unroll
    for (int mt = 0; mt < 4; ++mt)
#pragma unroll
        for (int nt = 0; nt < 4; ++nt) {
            int dd = nt * 16 + l15;
#pragma unroll
            for (int r = 0; r < 4; ++r) {
                int oc = wv * 64 + mt * 16 + lq * 4 + r;
                M[((size_t)b * 256 + oc) * 256 + h * 64 + dd] = f2bf(acc[mt][nt][r]);
            }
        }
}

// ---------------- 1x1 conv MFMA (BN=64, dbuf) -> xcatT pixel-major ----------
// K=512: c<256 pose (A=wF, B=xpm); c>=256 folded-attn (A=M_b, B=qT half-res).
__global__ __launch_bounds__(256, 3) void conv1x1_mfma(const float* __restrict__ fb,
                                                       float* __restrict__ wsf) {
    int lin = blockIdx.x;
    int swz = (lin & 7) * 128 + (lin >> 3);
    int xh = swz & 1, y = (swz >> 1) & 127, oct = (swz >> 8) & 1, b = swz >> 9;
    int oc0 = oct * 128, x0 = xh * 64;
    const ushort_t* wF   = (const ushort_t*)(wsf + WF_OFF);
    const ushort_t* Mb   = (const ushort_t*)(wsf + M_OFF) + (size_t)b * 65536;
    const ushort_t* xpm  = (const ushort_t*)(wsf + BUF0_OFF);   // pose pixel-major
    const ushort_t* qT   = (const ushort_t*)(wsf + QT_OFF);
    ushort_t* xcatT      = (ushort_t*)(wsf + XCAT_OFF);

    __shared__ alignas(16) ushort_t As[2][128 * 64];
    __shared__ alignas(16) ushort_t Bs[2][64 * 64];
    int t = threadIdx.x, lane = t & 63, wv = t >> 6;
    int wm = wv >> 1, wn = wv & 1, l15 = lane & 15, lq = lane >> 4;
    f32x4 acc[4][2] = {};

    auto stage = [&](int chunk, int bufi) {
        int c0 = chunk << 6;
#pragma unroll
        for (int r = 0; r < 4; ++r) {
            int slot = t + r * 256;
            int row = slot >> 3, cbk = slot & 7;
            int sw = (cbk ^ (row & 7)) << 3;
            const ushort_t* src;
            if (c0 < 256) src = wF + ((size_t)(oc0 + row) * 512 + c0 + sw);
            else          src = Mb + ((size_t)(oc0 + row) * 256 + (c0 - 256) + sw);
            gload_lds16(src, (ushort_t*)As[bufi] + (((size_t)wv * 64 + r * 256) << 3));
        }
#pragma unroll
        for (int r = 0; r < 2; ++r) {
            int slot = t + r * 256;
            int n = slot >> 3, cbk = slot & 7;
            int x = x0 + n;
            int sw = (cbk ^ (n & 7)) << 3;
            const ushort_t* src;
            if (c0 < 256)
                src = xpm + (((size_t)b * HWP + (size_t)y * 128 + x) * 256 + c0 + sw);
            else
                src = qT + (((size_t)b * N2 + (size_t)(y >> 1) * 64 + (x >> 1)) * 256
                            + (c0 - 256) + sw);
            gload_lds16(src, (ushort_t*)Bs[bufi] + (((size_t)wv * 64 + r * 256) << 3));
        }
    };

    stage(0, 0);
    __syncthreads();
    int buf = 0;
    for (int chunk = 0; chunk < 8; ++chunk) {
        short8 af[4][2], bf[2][2];
#pragma unroll
        for (int m = 0; m < 4; ++m) {
            int row = wm * 64 + m * 16 + l15;
#pragma unroll
            for (int ks = 0; ks < 2; ++ks)
                af[m][ks] = *(const short8*)&As[buf][row * 64 + (((ks * 4 + lq) ^ (row & 7)) << 3)];
        }
#pragma unroll
        for (int n = 0; n < 2; ++n) {
            int col = wn * 32 + n * 16 + l15;
#pragma unroll
            for (int ks = 0; ks < 2; ++ks)
                bf[n][ks] = *(const short8*)&Bs[buf][col * 64 + (((ks * 4 + lq) ^ (col & 7)) << 3)];
        }
        if (chunk < 7) stage(chunk + 1, buf ^ 1);
#pragma unroll
        for (int ks = 0; ks < 2; ++ks)
#pragma unroll
            for (int m = 0; m < 4; ++m)
#pragma unroll
                for (int n = 0; n < 2; ++n)
                    acc[m][n] = __builtin_amdgcn_mfma_f32_16x16x32_bf16(
                        af[m][ks], bf[n][ks], acc[m][n], 0, 0, 0);
        __syncthreads();
        buf ^= 1;
    }
#pragma unroll
    for (int m = 0; m < 4; ++m)
#pragma unroll
        for (int n = 0; n < 2; ++n) {
            int col = x0 + wn * 32 + n * 16 + l15;
            int ocq = oc0 + wm * 64 + m * 16 + lq * 4;
            ushort4 o;
            o.x = f2bf(acc[m][n][0] + fb[ocq + 0]);
            o.y = f2bf(acc[m][n][1] + fb[ocq + 1]);
            o.z = f2bf(acc[m][n][2] + fb[ocq + 2]);
            o.w = f2bf(acc[m][n][3] + fb[ocq + 3]);
            *(ushort4*)&xcatT[((size_t)b * HWP + (size_t)y * 128 + col) * 256 + ocq] = o;
        }
}

// ---------------- 3x3 SAME conv: verified R13 structure (plain epilogue) -----
__global__ __launch_bounds__(256, 2) void conv3x3_mfma(const float* __restrict__ cb,
                                                       float* __restrict__ wsf) {
    int lin = blockIdx.x;
    int swz = (lin & 7) * 64 + (lin >> 3);   // XCD-contiguous
    int y = swz & 127, oct = (swz >> 7) & 1, b = swz >> 8;
    int oc0 = oct * 128;
    int py = y & 1, yh = y >> 1;

    const ushort_t* xcatT = (const ushort_t*)(wsf + XCAT_OFF);
    const ushort_t* prevT = (const ushort_t*)(wsf + PREVT_OFF);
    const ushort_t* wA3x  = (const ushort_t*)(wsf + WA3X_OFF);
    const ushort_t* wPP   = (const ushort_t*)(wsf + WPP_OFF);
    const ushort_t* zp    = (const ushort_t*)(wsf + ZP_OFF);
    ushort_t* y3          = (ushort_t*)(wsf + Y3_OFF);

    __shared__ alignas(16) ushort_t As[2 * 128 * 64];   // 32 KB (2 parity variants for prev)
    __shared__ alignas(16) ushort_t Bs[128 * 64];       // 16 KB
    int t = threadIdx.x, lane = t & 63, wv = t >> 6;
    int wm = wv >> 1, wn = wv & 1, l15 = lane & 15, lq = lane >> 4;
    f32x4 acc[4][4] = {};

    for (int chunk = 0; chunk < 52; ++chunk) {
        bool isPrev = chunk >= 36;
        if (!isPrev) {
            int tap = chunk >> 2, c0 = (chunk & 3) << 6;
            int fy = tap / 3, fx = tap - fy * 3;
            int yy = y + fy - 1;
#pragma unroll
            for (int r = 0; r < 4; ++r) {      // A: xcat weights [128 oc][64 c]
                int slot = t + r * 256;
                int row = slot >> 3, cbk = slot & 7;
                const ushort_t* src = wA3x + (((size_t)tap * 256 + oc0 + row) * 256
                                              + c0 + ((cbk ^ (row & 7)) << 3));
                gload_lds16(src, (ushort_t*)As + (((size_t)wv * 64 + r * 256) << 3));
            }
#pragma unroll
            for (int r = 0; r < 4; ++r) {      // B: xcat pixels (permuted x), zero page OOB
                int slot = t + r * 256;
                int n = slot >> 3, cbk = slot & 7;
                int x = 2 * (n & 63) + (n >> 6);
                int xx = x + fx - 1;
                int sw = (cbk ^ (n & 7)) << 3;
                bool ok = (yy >= 0) && (yy < 128) && (xx >= 0) && (xx < 128);
                const ushort_t* src = ok
                    ? xcatT + (((size_t)b * HWP + (size_t)yy * 128 + xx) * 256 + c0 + sw)
                    : zp;
                gload_lds16(src, (ushort_t*)Bs + (((size_t)wv * 64 + r * 256) << 3));
            }
        } else {
            int pi = chunk - 36;
            int tap4 = pi >> 2, c0 = (pi & 3) << 6;   // tap4 = j2*2 + i2
            int j2 = tap4 >> 1, i2 = tap4 & 1;
            int pr = yh + py + j2 - 1;
#pragma unroll
            for (int r = 0; r < 8; ++r) {      // A: BOTH col-parity weight variants
                int slot = t + r * 256;
                int p = slot >> 10, rem = slot & 1023;
                int row = rem >> 3, cbk = rem & 7;
                const ushort_t* src = wPP + (((size_t)((py * 2 + p) * 4 + tap4) * 256
                                              + oc0 + row) * 256 + c0 + ((cbk ^ (row & 7)) << 3));
                gload_lds16(src, (ushort_t*)As + (((size_t)wv * 64 + r * 256) << 3));
            }
#pragma unroll
            for (int r = 0; r < 4; ++r) {      // B: prev pixels (permuted x), zero page OOB
                int slot = t + r * 256;
                int n = slot >> 3, cbk = slot & 7;
                int pc = (n & 63) - 1 + i2 + (n >> 6);
                int sw = (cbk ^ (n & 7)) << 3;
                bool ok = (pr >= 0) && (pr < 64) && (pc >= 0) && (pc < 64);
                const ushort_t* src = ok
                    ? prevT + (((size_t)b * N2 + (size_t)pr * 64 + pc) * 256 + c0 + sw)
                    : zp;
                gload_lds16(src, (ushort_t*)Bs + (((size_t)wv * 64 + r * 256) << 3));
            }
        }
        __syncthreads();   // drains vmcnt -> LDS tiles ready
        int abase = isPrev ? wn * 8192 : 0;    // prev: wave's col-parity variant
#pragma unroll
        for (int ks = 0; ks < 2; ++ks) {
            short8 af[4], bf[4];
#pragma unroll
            for (int m = 0; m < 4; ++m) {
                int row = wm * 64 + m * 16 + l15;
                af[m] = *(const short8*)&As[abase + row * 64 + (((ks * 4 + lq) ^ (row & 7)) << 3)];
            }
#pragma unroll
            for (int n = 0; n < 4; ++n) {
                int col = wn * 64 + n * 16 + l15;
                bf[n] = *(const short8*)&Bs[col * 64 + (((ks * 4 + lq) ^ (col & 7)) << 3)];
            }
#pragma unroll
            for (int m = 0; m < 4; ++m)
#pragma unroll
                for (int n = 0; n < 4; ++n)
                    acc[m][n] = __builtin_amdgcn_mfma_f32_16x16x32_bf16(
                        af[m], bf[n], acc[m][n], 0, 0, 0);
        }
        __syncthreads();   // all reads done before next stage overwrites
    }

    // epilogue: bias + bf16 store (permuted col -> x); NO fused IN (R14 lesson)
#pragma unroll
    for (int m = 0; m < 4; ++m)
#pragma unroll
        for (int n = 0; n < 4; ++n) {
            int col = wn * 64 + n * 16 + l15;
            int x = 2 * (col & 63) + (col >> 6);
            size_t pxo = (size_t)y * 128 + x;
#pragma unroll
            for (int r = 0; r < 4; ++r) {
                int oc = oc0 + wm * 64 + m * 16 + lq * 4 + r;
                y3[((size_t)b * 256 + oc) * HWP + pxo] = f2bf(acc[m][n][r] + cb[oc]);
            }
        }
}

// ---------------- instance norm + relu (own sums, verified R13 form) ---------
__global__ __launch_bounds__(256) void inorm_relu_k(const float* __restrict__ wsf,
                                                    float* __restrict__ out) {
    int bc = blockIdx.x;   // b*256+oc
    const ushort_t* yp = (const ushort_t*)(wsf + Y3_OFF) + (size_t)bc * HWP;
    int t = threadIdx.x;
    float s1 = 0.f, s2 = 0.f;
#pragma unroll
    for (int i = 0; i < 8; ++i) {
        short8 v = *(const short8*)&yp[(size_t)(t + i * 256) * 8];
#pragma unroll
        for (int j = 0; j < 8; ++j) {
            float f = bf2f((ushort_t)v[j]);
            s1 += f; s2 += f * f;
        }
    }
#pragma unroll
    for (int o = 32; o; o >>= 1) {
        s1 += __shfl_xor(s1, o, 64);
        s2 += __shfl_xor(s2, o, 64);
    }
    __shared__ float r1[4], r2[4];
    if ((t & 63) == 0) { r1[t >> 6] = s1; r2[t >> 6] = s2; }
    __syncthreads();
    float S1 = r1[0] + r1[1] + r1[2] + r1[3];
    float S2 = r2[0] + r2[1] + r2[2] + r2[3];
    float mean = S1 * (1.f / HWP);
    float var  = S2 * (1.f / HWP) - mean * mean;
    float inv  = rsqrtf(var + EPSI);
    float* op = out + (size_t)bc * HWP;
#pragma unroll
    for (int i = 0; i < 8; ++i) {
        int base = (t + i * 256) * 8;
        short8 v = *(const short8*)&yp[(size_t)base];
        float4 o0, o1;
        o0.x = fmaxf((bf2f((ushort_t)v[0]) - mean) * inv, 0.f);
        o0.y = fmaxf((bf2f((ushort_t)v[1]) - mean) * inv, 0.f);
        o0.z = fmaxf((bf2f((ushort_t)v[2]) - mean) * inv, 0.f);
        o0.w = fmaxf((bf2f((ushort_t)v[3]) - mean) * inv, 0.f);
        o1.x = fmaxf((bf2f((ushort_t)v[4]) - mean) * inv, 0.f);
        o1.y = fmaxf((bf2f((ushort_t)v[5]) - mean) * inv, 0.f);
        o1.z = fmaxf((bf2f((ushort_t)v[6]) - mean) * inv, 0.f);
        o1.w = fmaxf((bf2f((ushort_t)v[7]) - mean) * inv, 0.f);
        *(float4*)&op[base]     = o0;
        *(float4*)&op[base + 4] = o1;
    }
}

extern "C" void kernel_launch(void* const* d_in, const int* in_sizes, int n_in,
                              void* d_out, int out_size, void* d_ws, size_t ws_size,
                              hipStream_t stream)
{
    (void)in_sizes; (void)n_in; (void)out_size; (void)ws_size;
    const float* app_enc  = (const float*)d_in[0];
    const float* app_pose = (const float*)d_in[1];
    const float* pose_enc = (const float*)d_in[2];
    const float* prev_inp = (const float*)d_in[3];
    const float* qw = (const float*)d_in[4];
    const float* qb = (const float*)d_in[5];
    const float* kw = (const float*)d_in[6];
    const float* kb = (const float*)d_in[7];
    const float* vw = (const float*)d_in[8];
    const float* vb = (const float*)d_in[9];
    const float* gamma = (const float*)d_in[10];
    const float* fw = (const float*)d_in[11];
    const float* fb = (const float*)d_in[12];
    const float* cw = (const float*)d_in[13];
    const float* cb = (const float*)d_in[14];
    float* ws  = (float*)d_ws;
    float* out = (float*)d_out;

    // 1. weight packs + prevT + zero-init
    prep_k<<<dim3(512, 7), 256, 0, stream>>>(qw, kw, vw, fw, cw, prev_inp, ws);
    // 2. app_enc -> BUF0, app_pose -> BUF1
    xpm2_k<<<dim3(128, 4, 4), 256, 0, stream>>>(app_enc, app_pose, ws);
    // 3. v (BUF0) and k (BUF1) projections, merged
    kv_mfma<<<dim3(128, 2, 4), 256, 0, stream>>>(kb, vb, ws);
    // 4. S = v k^T (256 blocks)
    attn_S_mfma<<<dim3(32, 8), 64, 0, stream>>>(ws);
    // 5. pose -> BUF0
    xpmP_k<<<dim3(128, 4, 2), 256, 0, stream>>>(pose_enc, ws);
    // 6. q projection (gamma/8 folded, pixel-major)
    q_mfma<<<dim3(128, 2, 2), 256, 0, stream>>>(qb, gamma, ws);
    // 7. M = W_att x S (replaces attn_O)
    attn_M_mfma<<<8, 256, 0, stream>>>(ws);
    // 8. 1x1 conv: pose half + folded-attn half (M x qT) -> xcatT
    conv1x1_mfma<<<1024, 256, 0, stream>>>(fb, ws);
    // 9. 3x3 conv: 52 chunks, plain epilogue -> y3 (BUF1)
    conv3x3_mfma<<<512, 256, 0, stream>>>(cb, ws);
    // 10. instance norm + relu (own sums) -> f32 out
    inorm_relu_k<<<512, 256, 0, stream>>>(ws, out);
}

// Round 16
// 175.682 us; speedup vs baseline: 1.1698x; 1.0275x over previous
//
#include <hip/hip_runtime.h>
#include <hip/hip_bf16.h>

#define N2   4096    // 64*64 attn pixels
#define HWP  16384   // 128*128
#define EPSI 1e-5f

typedef unsigned short ushort_t;
typedef __attribute__((ext_vector_type(8))) short short8;
typedef __attribute__((ext_vector_type(4))) float f32x4;

// ---- workspace layout (f32-word offsets), peak 18,089,024 words = 72.4 MB ----
static const size_t BUF0_OFF  = 0;          // bf16 [2][16384][256]
static const size_t BUF1_OFF  = 4194304;    // bf16 [2][16384][256]  (later y3)
static const size_t QT_OFF    = 8388608;    // bf16 [2][4096][256]  q pixel-major (gamma/8 folded)
static const size_t KC_OFF    = 9437184;    // bf16 [2][256][4096]  k channel-major; later M[2][256][256]
static const size_t VC_OFF    = 10485760;   // bf16 [2][256][4096]
static const size_t S_OFF     = 11534336;   // f32 [8][64][64]   --- zero region start
static const size_t SUM_OFF   = 11567104;   // f32 [512] (unused)
static const size_t SUM2_OFF  = 11567616;   // f32 [512] (unused)
static const size_t ZP_OFF    = 11568128;   // f32 [64] zero page --- zero region end (33,856)
static const size_t XCAT_OFF  = 11568192;   // bf16 [2][16384][256] conv1x1 out pixel-major
static const size_t PREVT_OFF = 15762496;   // bf16 [2][4096][256]  prev pixel-major (unpadded)
static const size_t WQ_OFF    = 16811072;   // bf16 [4][256][256]
static const size_t WK_OFF    = 16942144;
static const size_t WV_OFF    = 17073216;
static const size_t WF_OFF    = 17204288;   // bf16 [256][512]
static const size_t WA3X_OFF  = 17269824;   // bf16 [9][256][256]  3x3 weights, xcat channels
static const size_t WPP_OFF   = 17564736;   // bf16 [16][256][256] row+col-collapsed prev weights
static const size_t Y3_OFF    = BUF1_OFF;
static const size_t M_OFF     = KC_OFF;     // bf16 [2][256][256] = W_att x S (aliases dead k)

__device__ __forceinline__ ushort_t f2bf(float x) {
    union { float f; unsigned u; } v; v.f = x;
    unsigned r = v.u + 0x7FFFu + ((v.u >> 16) & 1u);
    return (ushort_t)(r >> 16);
}
__device__ __forceinline__ float bf2f(ushort_t h) {
    union { unsigned u; float f; } v; v.u = ((unsigned)h) << 16; return v.f;
}
__device__ __forceinline__ void gload_lds16(const void* g, void* l) {
    __builtin_amdgcn_global_load_lds(
        (const __attribute__((address_space(1))) void*)g,
        (__attribute__((address_space(3))) void*)l, 16, 0, 0);
}

// ---------------- prep: weight packs + prevT + zero-init ----------------
__global__ __launch_bounds__(256) void prep_k(const float* __restrict__ qw,
                                              const float* __restrict__ kw,
                                              const float* __restrict__ vw,
                                              const float* __restrict__ fw,
                                              const float* __restrict__ cw,
                                              const float* __restrict__ prev,
                                              float* __restrict__ wsf) {
    __shared__ ushort_t T[64][64];
    int sec = blockIdx.y, bx = blockIdx.x, t = threadIdx.x;
    if (sec < 3) {               // pack q/k/v weights: [oc][c][2][2] -> wA[tap][oc][c]
        if (bx >= 256) return;
        int idx = bx * 256 + t;
        const float* src = sec == 0 ? qw : (sec == 1 ? kw : vw);
        ushort_t* dst = (ushort_t*)(wsf + (sec == 0 ? WQ_OFF : (sec == 1 ? WK_OFF : WV_OFF)));
        float4 v = *(const float4*)&src[(size_t)idx * 4];
        dst[0 * 65536 + idx] = f2bf(v.x);
        dst[1 * 65536 + idx] = f2bf(v.y);
        dst[2 * 65536 + idx] = f2bf(v.z);
        dst[3 * 65536 + idx] = f2bf(v.w);
    } else if (sec == 3) {       // pack fw
        int idx = bx * 256 + t;
        ((ushort_t*)(wsf + WF_OFF))[idx] = f2bf(fw[idx]);
    } else if (sec == 4) {       // pack 3x3 weights: xcat taps + row+col-collapsed prev taps
        int idx = bx * 256 + t;  // oc*512 + c
        int oc = idx >> 9, c = idx & 511;
        const float* src = cw + (size_t)idx * 9;
        float w[9];
#pragma unroll
        for (int tp = 0; tp < 9; ++tp) w[tp] = src[tp];
        if (c < 256) {
            ushort_t* wA3x = (ushort_t*)(wsf + WA3X_OFF);
#pragma unroll
            for (int tp = 0; tp < 9; ++tp)
                wA3x[((size_t)tp * 256 + oc) * 256 + c] = f2bf(w[tp]);
        } else {
            int cc = c - 256;
            ushort_t* wPP = (ushort_t*)(wsf + WPP_OFF);
#pragma unroll
            for (int py = 0; py < 2; ++py) {
                float rs[2][3];
#pragma unroll
                for (int fx = 0; fx < 3; ++fx) {
                    if (py == 0) { rs[0][fx] = w[fx];           rs[1][fx] = w[3 + fx] + w[6 + fx]; }
                    else         { rs[0][fx] = w[fx] + w[3 + fx]; rs[1][fx] = w[6 + fx]; }
                }
#pragma unroll
                for (int pxp = 0; pxp < 2; ++pxp)
#pragma unroll
                    for (int j2 = 0; j2 < 2; ++j2) {
                        float v0 = pxp == 0 ? rs[j2][0] : rs[j2][0] + rs[j2][1];
                        float v1 = pxp == 0 ? rs[j2][1] + rs[j2][2] : rs[j2][2];
                        wPP[(((size_t)((py * 2 + pxp) * 4 + j2 * 2 + 0)) * 256 + oc) * 256 + cc] = f2bf(v0);
                        wPP[(((size_t)((py * 2 + pxp) * 4 + j2 * 2 + 1)) * 256 + oc) * 256 + cc] = f2bf(v1);
                    }
            }
        }
    } else if (sec == 5) {       // prevT: [b][256][64][64] -> [b][4096][256] (unpadded)
        int y2 = bx & 63, ct = (bx >> 6) & 3, b = bx >> 8;
        ushort_t* pT = (ushort_t*)(wsf + PREVT_OFF);
#pragma unroll
        for (int i = 0; i < 4; ++i) {
            int s = t + i * 256;
            int cc = s >> 4, xq = s & 15;
            float4 v = *(const float4*)&prev[(((size_t)b * 256 + ct * 64 + cc) * 64 + y2) * 64 + xq * 4];
            ushort4 h; h.x = f2bf(v.x); h.y = f2bf(v.y); h.z = f2bf(v.z); h.w = f2bf(v.w);
            *(ushort4*)&T[cc][xq * 4] = h;
        }
        __syncthreads();
#pragma unroll
        for (int i = 0; i < 2; ++i) {
            int w = t * 2 + i;
            int px = w >> 3, cbk = w & 7;
            short8 o;
#pragma unroll
            for (int j = 0; j < 8; ++j) o[j] = (short)T[cbk * 8 + j][px];
            *(short8*)&pT[((size_t)b * N2 + (size_t)y2 * 64 + px) * 256 + ct * 64 + cbk * 8] = o;
        }
    } else {                     // zero S/SUM/SUM2/ZP
        int idx = bx * 256 + t;
        if (idx < 33856) wsf[S_OFF + idx] = 0.f;
    }
}

// ---------------- input -> pixel-major bf16 ----------------
__device__ __forceinline__ void xpm_body(const float* __restrict__ in, ushort_t* __restrict__ xpm,
                                         int y, int ct, int b, int t) {
    __shared__ ushort_t T[64][128];
#pragma unroll
    for (int i = 0; i < 8; ++i) {
        int s = t + i * 256;
        int cc = s >> 5, xq = s & 31;
        float4 v = *(const float4*)&in[(((size_t)b * 256 + ct * 64 + cc) * 128 + y) * 128 + xq * 4];
        ushort4 h; h.x = f2bf(v.x); h.y = f2bf(v.y); h.z = f2bf(v.z); h.w = f2bf(v.w);
        *(ushort4*)&T[cc][xq * 4] = h;
    }
    __syncthreads();
#pragma unroll
    for (int i = 0; i < 4; ++i) {
        int w = t * 4 + i;
        int px = w >> 3, cbk = w & 7;
        short8 o;
#pragma unroll
        for (int j = 0; j < 8; ++j) o[j] = (short)T[cbk * 8 + j][px];
        *(short8*)&xpm[(((size_t)b * HWP) + (size_t)y * 128 + px) * 256 + ct * 64 + cbk * 8] = o;
    }
}

__global__ __launch_bounds__(256) void xpm2_k(const float* __restrict__ app,
                                              const float* __restrict__ app_pose,
                                              float* __restrict__ wsf) {
    int z = blockIdx.z, which = z >> 1, b = z & 1;
    const float* in = which == 0 ? app : app_pose;
    ushort_t* dst = (ushort_t*)(wsf + (which == 0 ? BUF0_OFF : BUF1_OFF));
    xpm_body(in, dst, blockIdx.x, blockIdx.y, b, threadIdx.x);
}

__global__ __launch_bounds__(256) void xpmP_k(const float* __restrict__ pose,
                                              float* __restrict__ wsf) {
    xpm_body(pose, (ushort_t*)(wsf + BUF0_OFF), blockIdx.x, blockIdx.y, blockIdx.z, threadIdx.x);
}

// ---------------- qkv stride-2 2x2 conv GEMM body (BN=64, dbuf) ----------------
template<int MODE>
__device__ __forceinline__ void qkv_body(int nb, int oct, int b,
                                         const float* __restrict__ bias,
                                         const float* __restrict__ gamma,
                                         const ushort_t* __restrict__ wA,
                                         const ushort_t* __restrict__ xpm,
                                         ushort_t* __restrict__ outp) {
    int n0 = nb * 64, oc0 = oct * 128;
    __shared__ alignas(16) ushort_t As[2][128 * 64];
    __shared__ alignas(16) ushort_t Bs[2][64 * 64];
    int t = threadIdx.x, lane = t & 63, wv = t >> 6;
    int wm = wv >> 1, wn = wv & 1, l15 = lane & 15, lq = lane >> 4;
    f32x4 acc[4][2] = {};

    auto stage = [&](int chunk, int bufi) {
        int tap = chunk >> 2, c0 = (chunk & 3) << 6;
        int fy = tap >> 1, fx = tap & 1;
#pragma unroll
        for (int r = 0; r < 4; ++r) {          // A: 1024 slots
            int slot = t + r * 256;
            int row = slot >> 3, cbk = slot & 7;
            const ushort_t* src = wA + ((size_t)tap * 65536 + (size_t)(oc0 + row) * 256
                                        + c0 + ((cbk ^ (row & 7)) << 3));
            gload_lds16(src, (ushort_t*)As[bufi] + (((size_t)wv * 64 + r * 256) << 3));
        }
#pragma unroll
        for (int r = 0; r < 2; ++r) {          // B: 512 slots
            int slot = t + r * 256;
            int n = slot >> 3, cbk = slot & 7;
            int ng = n0 + n;
            int iy = ((ng >> 6) << 1) + fy, ix = ((ng & 63) << 1) + fx;
            const ushort_t* src = xpm + (((size_t)b * HWP + (size_t)iy * 128 + ix) * 256
                                         + c0 + ((cbk ^ (n & 7)) << 3));
            gload_lds16(src, (ushort_t*)Bs[bufi] + (((size_t)wv * 64 + r * 256) << 3));
        }
    };

    stage(0, 0);
    __syncthreads();
    int buf = 0;
    for (int chunk = 0; chunk < 16; ++chunk) {
        short8 af[4][2], bf[2][2];
#pragma unroll
        for (int m = 0; m < 4; ++m) {
            int row = wm * 64 + m * 16 + l15;
#pragma unroll
            for (int ks = 0; ks < 2; ++ks)
                af[m][ks] = *(const short8*)&As[buf][row * 64 + (((ks * 4 + lq) ^ (row & 7)) << 3)];
        }
#pragma unroll
        for (int n = 0; n < 2; ++n) {
            int col = wn * 32 + n * 16 + l15;
#pragma unroll
            for (int ks = 0; ks < 2; ++ks)
                bf[n][ks] = *(const short8*)&Bs[buf][col * 64 + (((ks * 4 + lq) ^ (col & 7)) << 3)];
        }
        if (chunk < 15) stage(chunk + 1, buf ^ 1);
#pragma unroll
        for (int ks = 0; ks < 2; ++ks)
#pragma unroll
            for (int m = 0; m < 4; ++m)
#pragma unroll
                for (int n = 0; n < 2; ++n)
                    acc[m][n] = __builtin_amdgcn_mfma_f32_16x16x32_bf16(
                        af[m][ks], bf[n][ks], acc[m][n], 0, 0, 0);
        __syncthreads();
        buf ^= 1;
    }
#pragma unroll
    for (int m = 0; m < 4; ++m)
#pragma unroll
        for (int n = 0; n < 2; ++n) {
            int col = wn * 32 + n * 16 + l15;
            int ng = n0 + col;
            int ocq = oc0 + wm * 64 + m * 16 + lq * 4;
            if (MODE == 0) {
                ushort4 o;
                float s0 = gamma[ocq >> 6] * 0.125f;
                o.x = f2bf((acc[m][n][0] + bias[ocq + 0]) * s0);
                o.y = f2bf((acc[m][n][1] + bias[ocq + 1]) * s0);
                o.z = f2bf((acc[m][n][2] + bias[ocq + 2]) * s0);
                o.w = f2bf((acc[m][n][3] + bias[ocq + 3]) * s0);
                *(ushort4*)&outp[((size_t)b * N2 + ng) * 256 + ocq] = o;
            } else {
#pragma unroll
                for (int r = 0; r < 4; ++r)
                    outp[((size_t)(b * 256 + ocq + r)) * N2 + ng] = f2bf(acc[m][n][r] + bias[ocq + r]);
            }
        }
}

__global__ __launch_bounds__(256, 3) void kv_mfma(const float* __restrict__ kb_,
                                                  const float* __restrict__ vb_,
                                                  float* __restrict__ wsf) {
    int z = blockIdx.z, cv = z >> 1, b = z & 1;
    const ushort_t* wA  = (const ushort_t*)(wsf + (cv == 0 ? WV_OFF : WK_OFF));
    const ushort_t* xpm = (const ushort_t*)(wsf + (cv == 0 ? BUF0_OFF : BUF1_OFF));
    const float* bias   = cv == 0 ? vb_ : kb_;
    ushort_t* outp      = (ushort_t*)(wsf + (cv == 0 ? VC_OFF : KC_OFF));
    qkv_body<1>(blockIdx.x, blockIdx.y, b, bias, nullptr, wA, xpm, outp);
}

__global__ __launch_bounds__(256, 3) void q_mfma(const float* __restrict__ qb_,
                                                 const float* __restrict__ gamma,
                                                 float* __restrict__ wsf) {
    qkv_body<0>(blockIdx.x, blockIdx.y, blockIdx.z, qb_, gamma,
                (const ushort_t*)(wsf + WQ_OFF), (const ushort_t*)(wsf + BUF0_OFF),
                (ushort_t*)(wsf + QT_OFF));
}

// ---------------- S[d][d'] = sum_m v[d][m] k[d'][m]  (MFMA, atomic f32) ------
__global__ __launch_bounds__(64) void attn_S_mfma(float* __restrict__ wsf) {
    int mc = blockIdx.x, bh = blockIdx.y;
    int b = bh >> 2, h = bh & 3;
    const ushort_t* vp = (const ushort_t*)(wsf + VC_OFF) + (size_t)(b * 256 + h * 64) * N2;
    const ushort_t* kp = (const ushort_t*)(wsf + KC_OFF) + (size_t)(b * 256 + h * 64) * N2;
    float* Sp = wsf + S_OFF + (size_t)bh * 4096;
    int lane = threadIdx.x, l15 = lane & 15, lq = lane >> 4;
    f32x4 acc[4][4] = {};
    for (int m0 = mc * 128; m0 < mc * 128 + 128; m0 += 32) {
        short8 af[4], bf[4];
#pragma unroll
        for (int mt = 0; mt < 4; ++mt)
            af[mt] = *(const short8*)&vp[(size_t)(mt * 16 + l15) * N2 + m0 + lq * 8];
#pragma unroll
        for (int nt = 0; nt < 4; ++nt)
            bf[nt] = *(const short8*)&kp[(size_t)(nt * 16 + l15) * N2 + m0 + lq * 8];
#pragma unroll
        for (int mt = 0; mt < 4; ++mt)
#pragma unroll
            for (int nt = 0; nt < 4; ++nt)
                acc[mt][nt] = __builtin_amdgcn_mfma_f32_16x16x32_bf16(
                    af[mt], bf[nt], acc[mt][nt], 0, 0, 0);
    }
#pragma unroll
    for (int mt = 0; mt < 4; ++mt)
#pragma unroll
        for (int nt = 0; nt < 4; ++nt)
#pragma unroll
            for (int r = 0; r < 4; ++r)
                atomicAdd(&Sp[(mt * 16 + lq * 4 + r) * 64 + nt * 16 + l15], acc[mt][nt][r]);
}

// ---------------- M[b][oc][h*64+d''] = sum_d W_att[oc][h*64+d] S_bh[d][d''] ----
__global__ __launch_bounds__(256) void attn_M_mfma(float* __restrict__ wsf) {
    int bh = blockIdx.x;
    int b = bh >> 2, h = bh & 3;
    const float* Sp = wsf + S_OFF + (size_t)bh * 4096;
    const ushort_t* wF = (const ushort_t*)(wsf + WF_OFF);
    ushort_t* M = (ushort_t*)(wsf + M_OFF);
    __shared__ ushort_t SlT[64][72];   // S transposed: SlT[d''][d]
    int t = threadIdx.x;
#pragma unroll
    for (int g = 0; g < 4; ++g) {
        int idx = t * 16 + g * 4;
        float4 v = *(const float4*)&Sp[idx];
        int d = idx >> 6, dd = idx & 63;
        SlT[dd + 0][d] = f2bf(v.x);
        SlT[dd + 1][d] = f2bf(v.y);
        SlT[dd + 2][d] = f2bf(v.z);
        SlT[dd + 3][d] = f2bf(v.w);
    }
    __syncthreads();
    int lane = t & 63, wv = t >> 6, l15 = lane & 15, lq = lane >> 4;
    f32x4 acc[4][4] = {};
#pragma unroll
    for (int ks = 0; ks < 2; ++ks) {
        short8 aw[4], bs[4];
#pragma unroll
        for (int mt = 0; mt < 4; ++mt) {
            int oc = wv * 64 + mt * 16 + l15;
            aw[mt] = *(const short8*)&wF[(size_t)oc * 512 + 256 + h * 64 + ks * 32 + lq * 8];
        }
#pragma unroll
        for (int nt = 0; nt < 4; ++nt)
            bs[nt] = *(const short8*)&SlT[nt * 16 + l15][ks * 32 + lq * 8];
#pragma unroll
        for (int mt = 0; mt < 4; ++mt)
#pragma unroll
            for (int nt = 0; nt < 4; ++nt)
                acc[mt][nt] = __builtin_amdgcn_mfma_f32_16x16x32_bf16(
                    aw[mt], bs[nt], acc[mt][nt], 0, 0, 0);
    }
#pragma unroll
    for (int mt = 0; mt < 4; ++mt)
#pragma unroll
        for (int nt = 0; nt < 4; ++nt) {
            int dd = nt * 16 + l15;
#pragma unroll
            for (int r = 0; r < 4; ++r) {
                int oc = wv * 64 + mt * 16 + lq * 4 + r;
                M[((size_t)b * 256 + oc) * 256 + h * 64 + dd] = f2bf(acc[mt][nt][r]);
            }
        }
}

// ---------------- 1x1 conv: BN=128 single-buf (conv3x3-style) -> xcatT --------
// K=512: c<256 pose (A=wF, B=xpm); c>=256 folded-attn (A=M_b, B=qT half-res).
__global__ __launch_bounds__(256, 2) void conv1x1_mfma(const float* __restrict__ fb,
                                                       float* __restrict__ wsf) {
    int lin = blockIdx.x;
    int swz = (lin & 7) * 64 + (lin >> 3);   // XCD-contiguous
    int y = swz & 127, oct = (swz >> 7) & 1, b = swz >> 8;
    int oc0 = oct * 128;
    const ushort_t* wF   = (const ushort_t*)(wsf + WF_OFF);
    const ushort_t* Mb   = (const ushort_t*)(wsf + M_OFF) + (size_t)b * 65536;
    const ushort_t* xpm  = (const ushort_t*)(wsf + BUF0_OFF);   // pose pixel-major
    const ushort_t* qT   = (const ushort_t*)(wsf + QT_OFF);
    ushort_t* xcatT      = (ushort_t*)(wsf + XCAT_OFF);

    __shared__ alignas(16) ushort_t As[128 * 64];
    __shared__ alignas(16) ushort_t Bs[128 * 64];
    int t = threadIdx.x, lane = t & 63, wv = t >> 6;
    int wm = wv >> 1, wn = wv & 1, l15 = lane & 15, lq = lane >> 4;
    f32x4 acc[4][4] = {};

    for (int chunk = 0; chunk < 8; ++chunk) {
        int c0 = chunk << 6;
#pragma unroll
        for (int r = 0; r < 4; ++r) {          // A: weights [128 oc][64 c]
            int slot = t + r * 256;
            int row = slot >> 3, cbk = slot & 7;
            int sw = (cbk ^ (row & 7)) << 3;
            const ushort_t* src;
            if (c0 < 256) src = wF + ((size_t)(oc0 + row) * 512 + c0 + sw);
            else          src = Mb + ((size_t)(oc0 + row) * 256 + (c0 - 256) + sw);
            gload_lds16(src, (ushort_t*)As + (((size_t)wv * 64 + r * 256) << 3));
        }
#pragma unroll
        for (int r = 0; r < 4; ++r) {          // B: pixels [128 n][64 c]
            int slot = t + r * 256;
            int n = slot >> 3, cbk = slot & 7;
            int sw = (cbk ^ (n & 7)) << 3;
            const ushort_t* src;
            if (c0 < 256)
                src = xpm + (((size_t)b * HWP + (size_t)y * 128 + n) * 256 + c0 + sw);
            else
                src = qT + (((size_t)b * N2 + (size_t)(y >> 1) * 64 + (n >> 1)) * 256
                            + (c0 - 256) + sw);
            gload_lds16(src, (ushort_t*)Bs + (((size_t)wv * 64 + r * 256) << 3));
        }
        __syncthreads();   // drains vmcnt -> LDS tiles ready
#pragma unroll
        for (int ks = 0; ks < 2; ++ks) {
            short8 af[4], bf[4];
#pragma unroll
            for (int m = 0; m < 4; ++m) {
                int row = wm * 64 + m * 16 + l15;
                af[m] = *(const short8*)&As[row * 64 + (((ks * 4 + lq) ^ (row & 7)) << 3)];
            }
#pragma unroll
            for (int n = 0; n < 4; ++n) {
                int col = wn * 64 + n * 16 + l15;
                bf[n] = *(const short8*)&Bs[col * 64 + (((ks * 4 + lq) ^ (col & 7)) << 3)];
            }
#pragma unroll
            for (int m = 0; m < 4; ++m)
#pragma unroll
                for (int n = 0; n < 4; ++n)
                    acc[m][n] = __builtin_amdgcn_mfma_f32_16x16x32_bf16(
                        af[m], bf[n], acc[m][n], 0, 0, 0);
        }
        __syncthreads();   // all reads done before next stage overwrites
    }
#pragma unroll
    for (int m = 0; m < 4; ++m)
#pragma unroll
        for (int n = 0; n < 4; ++n) {
            int col = wn * 64 + n * 16 + l15;
            int ocq = oc0 + wm * 64 + m * 16 + lq * 4;
            ushort4 o;
            o.x = f2bf(acc[m][n][0] + fb[ocq + 0]);
            o.y = f2bf(acc[m][n][1] + fb[ocq + 1]);
            o.z = f2bf(acc[m][n][2] + fb[ocq + 2]);
            o.w = f2bf(acc[m][n][3] + fb[ocq + 3]);
            *(ushort4*)&xcatT[((size_t)b * HWP + (size_t)y * 128 + col) * 256 + ocq] = o;
        }
}

// ---------------- 3x3 SAME conv: verified R13 structure (plain epilogue) -----
__global__ __launch_bounds__(256, 2) void conv3x3_mfma(const float* __restrict__ cb,
                                                       float* __restrict__ wsf) {
    int lin = blockIdx.x;
    int swz = (lin & 7) * 64 + (lin >> 3);   // XCD-contiguous
    int y = swz & 127, oct = (swz >> 7) & 1, b = swz >> 8;
    int oc0 = oct * 128;
    int py = y & 1, yh = y >> 1;

    const ushort_t* xcatT = (const ushort_t*)(wsf + XCAT_OFF);
    const ushort_t* prevT = (const ushort_t*)(wsf + PREVT_OFF);
    const ushort_t* wA3x  = (const ushort_t*)(wsf + WA3X_OFF);
    const ushort_t* wPP   = (const ushort_t*)(wsf + WPP_OFF);
    const ushort_t* zp    = (const ushort_t*)(wsf + ZP_OFF);
    ushort_t* y3          = (ushort_t*)(wsf + Y3_OFF);

    __shared__ alignas(16) ushort_t As[2 * 128 * 64];   // 32 KB (2 parity variants for prev)
    __shared__ alignas(16) ushort_t Bs[128 * 64];       // 16 KB
    int t = threadIdx.x, lane = t & 63, wv = t >> 6;
    int wm = wv >> 1, wn = wv & 1, l15 = lane & 15, lq = lane >> 4;
    f32x4 acc[4][4] = {};

    for (int chunk = 0; chunk < 52; ++chunk) {
        bool isPrev = chunk >= 36;
        if (!isPrev) {
            int tap = chunk >> 2, c0 = (chunk & 3) << 6;
            int fy = tap / 3, fx = tap - fy * 3;
            int yy = y + fy - 1;
#pragma unroll
            for (int r = 0; r < 4; ++r) {      // A: xcat weights [128 oc][64 c]
                int slot = t + r * 256;
                int row = slot >> 3, cbk = slot & 7;
                const ushort_t* src = wA3x + (((size_t)tap * 256 + oc0 + row) * 256
                                              + c0 + ((cbk ^ (row & 7)) << 3));
                gload_lds16(src, (ushort_t*)As + (((size_t)wv * 64 + r * 256) << 3));
            }
#pragma unroll
            for (int r = 0; r < 4; ++r) {      // B: xcat pixels (permuted x), zero page OOB
                int slot = t + r * 256;
                int n = slot >> 3, cbk = slot & 7;
                int x = 2 * (n & 63) + (n >> 6);
                int xx = x + fx - 1;
                int sw = (cbk ^ (n & 7)) << 3;
                bool ok = (yy >= 0) && (yy < 128) && (xx >= 0) && (xx < 128);
                const ushort_t* src = ok
                    ? xcatT + (((size_t)b * HWP + (size_t)yy * 128 + xx) * 256 + c0 + sw)
                    : zp;
                gload_lds16(src, (ushort_t*)Bs + (((size_t)wv * 64 + r * 256) << 3));
            }
        } else {
            int pi = chunk - 36;
            int tap4 = pi >> 2, c0 = (pi & 3) << 6;   // tap4 = j2*2 + i2
            int j2 = tap4 >> 1, i2 = tap4 & 1;
            int pr = yh + py + j2 - 1;
#pragma unroll
            for (int r = 0; r < 8; ++r) {      // A: BOTH col-parity weight variants
                int slot = t + r * 256;
                int p = slot >> 10, rem = slot & 1023;
                int row = rem >> 3, cbk = rem & 7;
                const ushort_t* src = wPP + (((size_t)((py * 2 + p) * 4 + tap4) * 256
                                              + oc0 + row) * 256 + c0 + ((cbk ^ (row & 7)) << 3));
                gload_lds16(src, (ushort_t*)As + (((size_t)wv * 64 + r * 256) << 3));
            }
#pragma unroll
            for (int r = 0; r < 4; ++r) {      // B: prev pixels (permuted x), zero page OOB
                int slot = t + r * 256;
                int n = slot >> 3, cbk = slot & 7;
                int pc = (n & 63) - 1 + i2 + (n >> 6);
                int sw = (cbk ^ (n & 7)) << 3;
                bool ok = (pr >= 0) && (pr < 64) && (pc >= 0) && (pc < 64);
                const ushort_t* src = ok
                    ? prevT + (((size_t)b * N2 + (size_t)pr * 64 + pc) * 256 + c0 + sw)
                    : zp;
                gload_lds16(src, (ushort_t*)Bs + (((size_t)wv * 64 + r * 256) << 3));
            }
        }
        __syncthreads();   // drains vmcnt -> LDS tiles ready
        int abase = isPrev ? wn * 8192 : 0;    // prev: wave's col-parity variant
#pragma unroll
        for (int ks = 0; ks < 2; ++ks) {
            short8 af[4], bf[4];
#pragma unroll
            for (int m = 0; m < 4; ++m) {
                int row = wm * 64 + m * 16 + l15;
                af[m] = *(const short8*)&As[abase + row * 64 + (((ks * 4 + lq) ^ (row & 7)) << 3)];
            }
#pragma unroll
            for (int n = 0; n < 4; ++n) {
                int col = wn * 64 + n * 16 + l15;
                bf[n] = *(const short8*)&Bs[col * 64 + (((ks * 4 + lq) ^ (col & 7)) << 3)];
            }
#pragma unroll
            for (int m = 0; m < 4; ++m)
#pragma unroll
                for (int n = 0; n < 4; ++n)
                    acc[m][n] = __builtin_amdgcn_mfma_f32_16x16x32_bf16(
                        af[m], bf[n], acc[m][n], 0, 0, 0);
        }
        __syncthreads();   // all reads done before next stage overwrites
    }

    // epilogue: bias + bf16 store (permuted col -> x); NO fused IN (R14 lesson)
#pragma unroll
    for (int m = 0; m < 4; ++m)
#pragma unroll
        for (int n = 0; n < 4; ++n) {
            int col = wn * 64 + n * 16 + l15;
            int x = 2 * (col & 63) + (col >> 6);
            size_t pxo = (size_t)y * 128 + x;
#pragma unroll
            for (int r = 0; r < 4; ++r) {
                int oc = oc0 + wm * 64 + m * 16 + lq * 4 + r;
                y3[((size_t)b * 256 + oc) * HWP + pxo] = f2bf(acc[m][n][r] + cb[oc]);
            }
        }
}

// ---------------- instance norm + relu (own sums, verified R13 form) ---------
__global__ __launch_bounds__(256) void inorm_relu_k(const float* __restrict__ wsf,
                                                    float* __restrict__ out) {
    int bc = blockIdx.x;   // b*256+oc
    const ushort_t* yp = (const ushort_t*)(wsf + Y3_OFF) + (size_t)bc * HWP;
    int t = threadIdx.x;
    float s1 = 0.f, s2 = 0.f;
#pragma unroll
    for (int i = 0; i < 8; ++i) {
        short8 v = *(const short8*)&yp[(size_t)(t + i * 256) * 8];
#pragma unroll
        for (int j = 0; j < 8; ++j) {
            float f = bf2f((ushort_t)v[j]);
            s1 += f; s2 += f * f;
        }
    }
#pragma unroll
    for (int o = 32; o; o >>= 1) {
        s1 += __shfl_xor(s1, o, 64);
        s2 += __shfl_xor(s2, o, 64);
    }
    __shared__ float r1[4], r2[4];
    if ((t & 63) == 0) { r1[t >> 6] = s1; r2[t >> 6] = s2; }
    __syncthreads();
    float S1 = r1[0] + r1[1] + r1[2] + r1[3];
    float S2 = r2[0] + r2[1] + r2[2] + r2[3];
    float mean = S1 * (1.f / HWP);
    float var  = S2 * (1.f / HWP) - mean * mean;
    float inv  = rsqrtf(var + EPSI);
    float* op = out + (size_t)bc * HWP;
#pragma unroll
    for (int i = 0; i < 8; ++i) {
        int base = (t + i * 256) * 8;
        short8 v = *(const short8*)&yp[(size_t)base];
        float4 o0, o1;
        o0.x = fmaxf((bf2f((ushort_t)v[0]) - mean) * inv, 0.f);
        o0.y = fmaxf((bf2f((ushort_t)v[1]) - mean) * inv, 0.f);
        o0.z = fmaxf((bf2f((ushort_t)v[2]) - mean) * inv, 0.f);
        o0.w = fmaxf((bf2f((ushort_t)v[3]) - mean) * inv, 0.f);
        o1.x = fmaxf((bf2f((ushort_t)v[4]) - mean) * inv, 0.f);
        o1.y = fmaxf((bf2f((ushort_t)v[5]) - mean) * inv, 0.f);
        o1.z = fmaxf((bf2f((ushort_t)v[6]) - mean) * inv, 0.f);
        o1.w = fmaxf((bf2f((ushort_t)v[7]) - mean) * inv, 0.f);
        *(float4*)&op[base]     = o0;
        *(float4*)&op[base + 4] = o1;
    }
}

extern "C" void kernel_launch(void* const* d_in, const int* in_sizes, int n_in,
                              void* d_out, int out_size, void* d_ws, size_t ws_size,
                              hipStream_t stream)
{
    (void)in_sizes; (void)n_in; (void)out_size; (void)ws_size;
    const float* app_enc  = (const float*)d_in[0];
    const float* app_pose = (const float*)d_in[1];
    const float* pose_enc = (const float*)d_in[2];
    const float* prev_inp = (const float*)d_in[3];
    const float* qw = (const float*)d_in[4];
    const float* qb = (const float*)d_in[5];
    const float* kw = (const float*)d_in[6];
    const float* kb = (const float*)d_in[7];
    const float* vw = (const float*)d_in[8];
    const float* vb = (const float*)d_in[9];
    const float* gamma = (const float*)d_in[10];
    const float* fw = (const float*)d_in[11];
    const float* fb = (const float*)d_in[12];
    const float* cw = (const float*)d_in[13];
    const float* cb = (const float*)d_in[14];
    float* ws  = (float*)d_ws;
    float* out = (float*)d_out;

    // 1. weight packs + prevT + zero-init
    prep_k<<<dim3(512, 7), 256, 0, stream>>>(qw, kw, vw, fw, cw, prev_inp, ws);
    // 2. app_enc -> BUF0, app_pose -> BUF1
    xpm2_k<<<dim3(128, 4, 4), 256, 0, stream>>>(app_enc, app_pose, ws);
    // 3. v (BUF0) and k (BUF1) projections, merged (BN=64 -> 512 blocks)
    kv_mfma<<<dim3(64, 2, 4), 256, 0, stream>>>(kb, vb, ws);
    // 4. S = v k^T (256 blocks)
    attn_S_mfma<<<dim3(32, 8), 64, 0, stream>>>(ws);
    // 5. pose -> BUF0
    xpmP_k<<<dim3(128, 4, 2), 256, 0, stream>>>(pose_enc, ws);
    // 6. q projection (gamma/8 folded, pixel-major, BN=64 -> 256 blocks)
    q_mfma<<<dim3(64, 2, 2), 256, 0, stream>>>(qb, gamma, ws);
    // 7. M = W_att x S (replaces attn_O)
    attn_M_mfma<<<8, 256, 0, stream>>>(ws);
    // 8. 1x1 conv (BN=128 single-buf): pose half + folded-attn half -> xcatT
    conv1x1_mfma<<<512, 256, 0, stream>>>(fb, ws);
    // 9. 3x3 conv: 52 chunks, plain epilogue -> y3 (BUF1)
    conv3x3_mfma<<<512, 256, 0, stream>>>(cb, ws);
    // 10. instance norm + relu (own sums) -> f32 out
    inorm_relu_k<<<512, 256, 0, stream>>>(ws, out);
}